// Round 2
// baseline (2999.475 us; speedup 1.0000x reference)
//
#include <hip/hip_runtime.h>
#include <hip/hip_bf16.h>
#include <math.h>

using bf16 = __hip_bfloat16;

static constexpr int B = 2, C = 192, Hh = 128, Ww = 128, N = Hh * Ww;
static constexpr int M = 128, RD = 10, GS = 256, NG = N / GS;        // 64 groups, no padding (N % GS == 0)
static constexpr int HEADS = 4, HD = C / HEADS;                      // 48
static constexpr int TDF = 16, HID = 4 * C, HIDT = HID + TDF;        // 768, 784
static constexpr int KS = 5, TC3 = 3 * C;                            // 576
static constexpr float LOG_M = 4.852030263919617f;                   // ln(128)

__device__ __forceinline__ float b2f(bf16 v) { return __bfloat162float(v); }
__device__ __forceinline__ bf16 f2b(float v) { return __float2bfloat16(v); }
__device__ __forceinline__ float gelu_exact(float v) {
    return 0.5f * v * (1.0f + erff(v * 0.70710678118654752f));
}

// ---------- K0: token-dict side precompute: kn (L2-normalized k), v, td_feat ----------
__global__ void k_precompute(const float* td, const float* wk_w, const float* wk_b,
                             const float* wv_w, const float* wv_b,
                             const float* fc_td_w, const float* fc_td_b,
                             float* kn, float* vv, float* tdf) {
    int m = blockIdx.x;          // 0..127
    int lane = threadIdx.x;      // 64
    __shared__ float trow[C];
    for (int ch = lane; ch < C; ch += 64) trow[ch] = td[m * C + ch];
    __syncthreads();
    __shared__ float ks[RD];
    __shared__ float inv_s;
    if (lane < RD) {
        float s = wk_b[lane];
        for (int ch = 0; ch < C; ++ch) s += trow[ch] * wk_w[ch * RD + lane];
        ks[lane] = s;
    }
    __syncthreads();
    if (lane == 0) {
        float ss = 0.f;
        for (int r = 0; r < RD; ++r) ss += ks[r] * ks[r];
        inv_s = 1.0f / fmaxf(sqrtf(ss), 1e-12f);
    }
    __syncthreads();
    if (lane < RD) kn[m * RD + lane] = ks[lane] * inv_s;
    for (int c0 = 0; c0 < 3; ++c0) {
        int co = lane + 64 * c0;
        float s = wv_b[co];
        for (int ch = 0; ch < C; ++ch) s += trow[ch] * wv_w[ch * C + co];
        vv[m * C + co] = s;
    }
    if (lane < TDF) {
        float s = fc_td_b[lane];
        for (int ch = 0; ch < C; ++ch) s += trow[ch] * fc_td_w[ch * TDF + lane];
        tdf[m * TDF + lane] = s;
    }
}

// ---------- K1: LN core (no gains): t[b,n,c] = (xs - mu) * rstd, stored bf16 ----------
__global__ void k_ln_t(const float* x, bf16* t) {
    int idx = blockIdx.x * blockDim.x + threadIdx.x;   // over B*N tokens
    if (idx >= B * N) return;
    int b = idx / N, i = idx % N;
    const float* xp = x + (size_t)b * C * N + i;
    float s = 0.f, ss = 0.f;
    for (int ch = 0; ch < C; ++ch) { float v = xp[(size_t)ch * N]; s += v; ss += v * v; }
    float mu = s / C;
    float rstd = rsqrtf(ss / C - mu * mu + 1e-5f);
    bf16* tp = t + (size_t)idx * C;
    for (int ch = 0; ch < C; ++ch) { float v = xp[(size_t)ch * N]; tp[ch] = f2b((v - mu) * rstd); }
}

// ---------- K2: ATD_CA fused: LN1(fp32) -> q -> cosine sim -> softmax+argmax -> sim@v ----------
// writes acc = shortcut + x_atd, and tk_id
__global__ void k_atdca(const float* x, const float* g1, const float* b1,
                        const float* wq_w, const float* wq_b, const float* ca_scale,
                        const float* kn, const float* vv,
                        float* acc, int* tk_id) {
    int idx = blockIdx.x;        // token (b*N+i)
    int b = idx / N, i = idx % N;
    int lane = threadIdx.x;      // 64
    const float* xp = x + (size_t)b * C * N + i;
    float xv[3];
    float s = 0.f, ssq = 0.f;
    #pragma unroll
    for (int k = 0; k < 3; ++k) {
        int ch = lane + 64 * k;
        float v = xp[(size_t)ch * N];
        xv[k] = v; s += v; ssq += v * v;
    }
    for (int mk = 32; mk >= 1; mk >>= 1) { s += __shfl_xor(s, mk); ssq += __shfl_xor(ssq, mk); }
    float mu = s / C;
    float rstd = rsqrtf(ssq / C - mu * mu + 1e-5f);
    float xn[3];
    #pragma unroll
    for (int k = 0; k < 3; ++k) {
        int ch = lane + 64 * k;
        xn[k] = (xv[k] - mu) * rstd * g1[ch] + b1[ch];
    }
    float q[RD];
    #pragma unroll
    for (int r = 0; r < RD; ++r) {
        float p = 0.f;
        #pragma unroll
        for (int k = 0; k < 3; ++k) { int ch = lane + 64 * k; p += xn[k] * wq_w[ch * RD + r]; }
        for (int mk = 32; mk >= 1; mk >>= 1) p += __shfl_xor(p, mk);
        q[r] = p + wq_b[r];
    }
    float ssn = 0.f;
    #pragma unroll
    for (int r = 0; r < RD; ++r) ssn += q[r] * q[r];
    float invq = 1.0f / fmaxf(sqrtf(ssn), 1e-12f);
    float s0 = 0.f, s1 = 0.f;
    #pragma unroll
    for (int r = 0; r < RD; ++r) {
        float qr = q[r] * invq;
        s0 += qr * kn[lane * RD + r];
        s1 += qr * kn[(lane + 64) * RD + r];
    }
    // argmax (first-max wins, matching jnp.argmax)
    float mv; int mi;
    if (s1 > s0) { mv = s1; mi = lane + 64; } else { mv = s0; mi = lane; }
    for (int mk = 32; mk >= 1; mk >>= 1) {
        float ov = __shfl_xor(mv, mk); int oi = __shfl_xor(mi, mk);
        if (ov > mv || (ov == mv && oi < mi)) { mv = ov; mi = oi; }
    }
    float cs = ca_scale[0]; cs = fminf(fmaxf(cs, 0.0f), 3.0f);
    float scale = 1.0f + cs * LOG_M;
    float e0 = expf((s0 - mv) * scale), e1 = expf((s1 - mv) * scale);
    float sum = e0 + e1;
    for (int mk = 32; mk >= 1; mk >>= 1) sum += __shfl_xor(sum, mk);
    float invs = 1.0f / sum;
    __shared__ float p_s[M];
    p_s[lane] = e0 * invs;
    p_s[lane + 64] = e1 * invs;
    __syncthreads();
    #pragma unroll
    for (int k = 0; k < 3; ++k) {
        int ch = lane + 64 * k;
        float a = 0.f;
        for (int m = 0; m < M; ++m) a += p_s[m] * vv[m * C + ch];
        acc[(size_t)idx * C + ch] = xv[k] + a;   // shortcut + x_atd
    }
    if (lane == 0) tk_id[idx] = mi;
}

// ---------- K3: qkv = (t*g1+b1) @ wqkv + b, naive tiled GEMM ----------
__global__ void k_qkv(const bf16* t, const float* g1, const float* b1,
                      const float* wqkv_w, const float* wqkv_b, bf16* qkv) {
    const int TT = 8;
    int tile = blockIdx.x;
    int tid = threadIdx.x;       // 256
    __shared__ float xt[TT][C];
    for (int idx = tid; idx < TT * C; idx += 256) {
        int tok = idx / C, ch = idx % C;
        int gi = tile * TT + tok;
        xt[tok][ch] = b2f(t[(size_t)gi * C + ch]) * g1[ch] + b1[ch];
    }
    __syncthreads();
    for (int sl = 0; sl < 3; ++sl) {
        int co = tid + 256 * sl;
        if (co >= TC3) break;
        float accv[TT];
        float bias = wqkv_b[co];
        #pragma unroll
        for (int tk = 0; tk < TT; ++tk) accv[tk] = bias;
        for (int ch = 0; ch < C; ++ch) {
            float w = wqkv_w[ch * TC3 + co];
            #pragma unroll
            for (int tk = 0; tk < TT; ++tk) accv[tk] += xt[tk][ch] * w;
        }
        #pragma unroll
        for (int tk = 0; tk < TT; ++tk)
            qkv[(size_t)(tile * TT + tk) * TC3 + co] = f2b(accv[tk]);
    }
}

// ---------- Stable counting sort by tk_id (3 kernels, chunked) ----------
__global__ void k_sort_count(const int* tk_id, int* chunk_cnt) {
    int c = blockIdx.x, b = blockIdx.y;  // 128 chunks x B
    int tid = threadIdx.x;               // 128
    __shared__ int cnt[M];
    cnt[tid] = 0;
    __syncthreads();
    atomicAdd(&cnt[tk_id[b * N + c * 128 + tid]], 1);
    __syncthreads();
    chunk_cnt[(b * 128 + c) * M + tid] = cnt[tid];
}

__global__ void k_sort_scan(int* chunk_cnt) {
    int b = blockIdx.x;
    int k = threadIdx.x;                 // 128 keys
    int tot = 0;
    for (int c = 0; c < 128; ++c) tot += chunk_cnt[(b * 128 + c) * M + k];
    __shared__ int totals[M];
    __shared__ int base[M];
    totals[k] = tot;
    __syncthreads();
    if (k == 0) {
        int run = 0;
        for (int kk = 0; kk < M; ++kk) { base[kk] = run; run += totals[kk]; }
    }
    __syncthreads();
    int run = base[k];
    for (int c = 0; c < 128; ++c) {
        int v = chunk_cnt[(b * 128 + c) * M + k];
        chunk_cnt[(b * 128 + c) * M + k] = run;   // overwrite count with base
        run += v;
    }
}

__global__ void k_sort_scatter(const int* tk_id, const int* chunk_cnt, int* sort_idx) {
    int c = blockIdx.x, b = blockIdx.y;
    int k = threadIdx.x;                 // 128 keys
    __shared__ int keys[128];
    keys[k] = tk_id[b * N + c * 128 + k];
    __syncthreads();
    int off = chunk_cnt[(b * 128 + c) * M + k];
    for (int j = 0; j < 128; ++j) {
        if (keys[j] == k) sort_idx[b * N + off++] = c * 128 + j;
    }
}

// ---------- K5: grouped self-attention, one query per thread ----------
__global__ void __launch_bounds__(256) k_attn(const bf16* qkv, const int* sort_idx, bf16* o_buf) {
    int g = blockIdx.x, hh = blockIdx.y, b = blockIdx.z;
    int tid = threadIdx.x;               // 256 = GS
    __shared__ int sidx[GS];
    __shared__ bf16 Kl[GS][HD];
    __shared__ bf16 Vl[GS][HD];
    sidx[tid] = sort_idx[b * N + g * GS + tid];
    __syncthreads();
    for (int idx = tid; idx < GS * HD; idx += 256) {
        int row = idx / HD, d = idx % HD;
        size_t base = ((size_t)(b * N + sidx[row])) * TC3 + hh * HD + d;
        Kl[row][d] = qkv[base + C];
        Vl[row][d] = qkv[base + 2 * C];
    }
    __syncthreads();
    float qv[HD];
    {
        size_t base = ((size_t)(b * N + sidx[tid])) * TC3 + hh * HD;
        #pragma unroll
        for (int d = 0; d < HD; ++d) qv[d] = b2f(qkv[base + d]) * 0.14433756729740643f; // 48^-0.5
    }
    float mmax = -1e30f, lsum = 0.f;
    for (int kk = 0; kk < GS; ++kk) {
        float sd = 0.f;
        #pragma unroll
        for (int d = 0; d < HD; ++d) sd += qv[d] * b2f(Kl[kk][d]);
        if (sd > mmax) { lsum = lsum * expf(mmax - sd) + 1.0f; mmax = sd; }
        else lsum += expf(sd - mmax);
    }
    float ov[HD];
    #pragma unroll
    for (int d = 0; d < HD; ++d) ov[d] = 0.f;
    for (int kk = 0; kk < GS; ++kk) {
        float sd = 0.f;
        #pragma unroll
        for (int d = 0; d < HD; ++d) sd += qv[d] * b2f(Kl[kk][d]);
        float p = expf(sd - mmax);
        #pragma unroll
        for (int d = 0; d < HD; ++d) ov[d] += p * b2f(Vl[kk][d]);
    }
    float inv = 1.0f / lsum;
    size_t obase = ((size_t)(b * N + sidx[tid])) * C + hh * HD;   // scatter = unsort
    #pragma unroll
    for (int d = 0; d < HD; ++d) o_buf[obase + d] = f2b(ov[d] * inv);
}

// ---------- K6: x_aca = o @ proj_w + proj_b, accumulated into acc ----------
__global__ void k_proj(const bf16* o_buf, const float* proj_w, const float* proj_b, float* acc) {
    const int TT = 8;
    int tile = blockIdx.x;
    int tid = threadIdx.x;               // 192
    __shared__ float ot[TT][C];
    for (int idx = tid; idx < TT * C; idx += 192) {
        int tok = idx / C, ch = idx % C;
        ot[tok][ch] = b2f(o_buf[(size_t)(tile * TT + tok) * C + ch]);
    }
    __syncthreads();
    int co = tid;
    float accv[TT];
    float bias = proj_b[co];
    #pragma unroll
    for (int t = 0; t < TT; ++t) accv[t] = bias;
    for (int ch = 0; ch < C; ++ch) {
        float w = proj_w[ch * C + co];
        #pragma unroll
        for (int t = 0; t < TT; ++t) accv[t] += ot[t][ch] * w;
    }
    #pragma unroll
    for (int t = 0; t < TT; ++t) acc[(size_t)(tile * TT + t) * C + co] += accv[t];
}

// ---------- K8: h1 = gelu((t*g2+b2)@fc1+b); hcat = [h1, td_feat[tk_id]] ----------
__global__ void k_fc1(const bf16* t, const float* g2, const float* b2v,
                      const float* fc1_w, const float* fc1_b,
                      const int* tk_id, const float* tdf, bf16* hcat) {
    const int TT = 8;
    int tile = blockIdx.x;
    int tid = threadIdx.x;               // 256
    __shared__ float xt[TT][C];
    for (int idx = tid; idx < TT * C; idx += 256) {
        int tok = idx / C, ch = idx % C;
        int gi = tile * TT + tok;
        xt[tok][ch] = b2f(t[(size_t)gi * C + ch]) * g2[ch] + b2v[ch];
    }
    __syncthreads();
    for (int sl = 0; sl < 3; ++sl) {
        int co = tid + 256 * sl;         // covers 0..767 exactly
        float accv[TT];
        float bias = fc1_b[co];
        #pragma unroll
        for (int t_ = 0; t_ < TT; ++t_) accv[t_] = bias;
        for (int ch = 0; ch < C; ++ch) {
            float w = fc1_w[ch * HID + co];
            #pragma unroll
            for (int t_ = 0; t_ < TT; ++t_) accv[t_] += xt[t_][ch] * w;
        }
        #pragma unroll
        for (int t_ = 0; t_ < TT; ++t_)
            hcat[(size_t)(tile * TT + t_) * HIDT + co] = f2b(gelu_exact(accv[t_]));
    }
    if (tid < TT * TDF) {
        int tok = tid / TDF, f = tid % TDF;
        int gi = tile * TT + tok;
        int m = tk_id[gi];
        hcat[(size_t)gi * HIDT + HID + f] = f2b(tdf[m * TDF + f]);
    }
}

// ---------- K9: depthwise 5x5 conv + gelu + residual (hcat + conv) ----------
__global__ void k_conv(const bf16* hcat, const float* dw_w, const float* dw_b, bf16* convsum) {
    int pos = blockIdx.x;                // B*N
    int b = pos / N, i = pos % N;
    int y = i / Ww, xx = i % Ww;
    int tid = threadIdx.x;               // 256
    for (int sl = 0; sl < 4; ++sl) {
        int ch = tid + 256 * sl;
        if (ch >= HIDT) break;
        float sum = 0.f;
        #pragma unroll
        for (int ky = 0; ky < KS; ++ky) {
            int yy = y + ky - 2;
            if (yy < 0 || yy >= Hh) continue;
            #pragma unroll
            for (int kx = 0; kx < KS; ++kx) {
                int xc = xx + kx - 2;
                if (xc < 0 || xc >= Ww) continue;
                float w = dw_w[ch * 25 + ky * KS + kx];
                sum += w * b2f(hcat[((size_t)(b * N + yy * Ww + xc)) * HIDT + ch]);
            }
        }
        sum += dw_b[ch];
        float center = b2f(hcat[(size_t)pos * HIDT + ch]);
        convsum[(size_t)pos * HIDT + ch] = f2b(center + gelu_exact(sum));
    }
}

// ---------- K10: x_ffn = LN3((hcat+conv) @ fc2 + b); out = acc + x_ffn (transposed) ----------
__global__ void __launch_bounds__(192) k_fc2_out(const bf16* convsum, const float* fc2_w, const float* fc2_b,
                                                 const float* g3, const float* b3, const float* acc, float* out) {
    const int TT = 8;
    int tile = blockIdx.x;
    int tid = threadIdx.x;               // 192
    __shared__ float rt[TT][HIDT];
    for (int idx = tid; idx < TT * HIDT; idx += 192) {
        int tok = idx / HIDT, ch = idx % HIDT;
        rt[tok][ch] = b2f(convsum[(size_t)(tile * TT + tok) * HIDT + ch]);
    }
    __syncthreads();
    float accv[TT];
    float bias = fc2_b[tid];
    #pragma unroll
    for (int t = 0; t < TT; ++t) accv[t] = bias;
    for (int ch = 0; ch < HIDT; ++ch) {
        float w = fc2_w[ch * C + tid];
        #pragma unroll
        for (int t = 0; t < TT; ++t) accv[t] += rt[t][ch] * w;
    }
    __shared__ float red[2][4];
    int wv = tid >> 6, lane = tid & 63;
    float g3v = g3[tid], b3v = b3[tid];
    for (int t = 0; t < TT; ++t) {
        float v = accv[t];
        float s = v, ss = v * v;
        for (int mk = 32; mk >= 1; mk >>= 1) { s += __shfl_xor(s, mk); ss += __shfl_xor(ss, mk); }
        if (lane == 0) { red[0][wv] = s; red[1][wv] = ss; }
        __syncthreads();
        float fs = red[0][0] + red[0][1] + red[0][2];
        float fss = red[1][0] + red[1][1] + red[1][2];
        float mu = fs / C;
        float rstd = rsqrtf(fss / C - mu * mu + 1e-5f);
        int gi = tile * TT + t;
        int b = gi / N, i = gi % N;
        float o = acc[(size_t)gi * C + tid] + (v - mu) * rstd * g3v + b3v;
        out[((size_t)b * C + tid) * N + i] = o;
        __syncthreads();
    }
}

__global__ void k_sentinel(float* out, int nelem) {
    int i = blockIdx.x * blockDim.x + threadIdx.x;
    if (i < nelem) out[i] = 1234.0f;
}

extern "C" void kernel_launch(void* const* d_in, const int* in_sizes, int n_in,
                              void* d_out, int out_size, void* d_ws, size_t ws_size,
                              hipStream_t stream) {
    const float* x        = (const float*)d_in[0];
    const float* td       = (const float*)d_in[2];
    const float* g1       = (const float*)d_in[3];
    const float* b1       = (const float*)d_in[4];
    const float* g2       = (const float*)d_in[5];
    const float* b2v      = (const float*)d_in[6];
    const float* g3       = (const float*)d_in[7];
    const float* b3       = (const float*)d_in[8];
    const float* wq_w     = (const float*)d_in[9];
    const float* wq_b     = (const float*)d_in[10];
    const float* wk_w     = (const float*)d_in[11];
    const float* wk_b     = (const float*)d_in[12];
    const float* wv_w     = (const float*)d_in[13];
    const float* wv_b     = (const float*)d_in[14];
    const float* ca_scale = (const float*)d_in[15];
    const float* wqkv_w   = (const float*)d_in[16];
    const float* wqkv_b   = (const float*)d_in[17];
    const float* proj_w   = (const float*)d_in[18];
    const float* proj_b   = (const float*)d_in[19];
    const float* fc_td_w  = (const float*)d_in[20];
    const float* fc_td_b  = (const float*)d_in[21];
    const float* fc1_w    = (const float*)d_in[22];
    const float* fc1_b    = (const float*)d_in[23];
    const float* dw_w     = (const float*)d_in[24];
    const float* dw_b     = (const float*)d_in[25];
    const float* fc2_w    = (const float*)d_in[26];
    const float* fc2_b    = (const float*)d_in[27];
    float* out = (float*)d_out;

    char* ws = (char*)d_ws;
    size_t off = 0;
    auto alloc = [&](size_t bytes) { size_t o = off; off += (bytes + 255) & ~(size_t)255; return o; };
    size_t o_t       = alloc((size_t)B * N * C * 2);        // t  (bf16)
    size_t o_acc     = alloc((size_t)B * N * C * 4);        // acc (fp32)
    size_t o_qkv     = alloc((size_t)B * N * TC3 * 2);      // qkv (bf16)
    size_t o_obuf    = alloc((size_t)B * N * C * 2);        // attn out, unsorted (bf16)
    size_t o_hcat    = alloc((size_t)B * N * HIDT * 2);     // hcat (bf16)
    size_t o_conv    = alloc((size_t)B * N * HIDT * 2);     // hcat+gelu(conv) (bf16)
    size_t o_kn      = alloc((size_t)M * RD * 4);
    size_t o_vv      = alloc((size_t)M * C * 4);
    size_t o_tdf     = alloc((size_t)M * TDF * 4);
    size_t o_tk      = alloc((size_t)B * N * 4);
    size_t o_sidx    = alloc((size_t)B * N * 4);
    size_t o_ccnt    = alloc((size_t)B * 128 * M * 4);

    if (ws_size < off) {  // unambiguous sentinel if workspace is too small
        k_sentinel<<<(out_size + 255) / 256, 256, 0, stream>>>(out, out_size);
        return;
    }

    bf16*  t_buf   = (bf16*)(ws + o_t);
    float* acc     = (float*)(ws + o_acc);
    bf16*  qkv     = (bf16*)(ws + o_qkv);
    bf16*  o_bufp  = (bf16*)(ws + o_obuf);
    bf16*  hcat    = (bf16*)(ws + o_hcat);
    bf16*  convsum = (bf16*)(ws + o_conv);
    float* kn      = (float*)(ws + o_kn);
    float* vv      = (float*)(ws + o_vv);
    float* tdf     = (float*)(ws + o_tdf);
    int*   tk_id   = (int*)(ws + o_tk);
    int*   sidx    = (int*)(ws + o_sidx);
    int*   ccnt    = (int*)(ws + o_ccnt);

    k_precompute<<<M, 64, 0, stream>>>(td, wk_w, wk_b, wv_w, wv_b, fc_td_w, fc_td_b, kn, vv, tdf);
    k_ln_t<<<(B * N + 255) / 256, 256, 0, stream>>>(x, t_buf);
    k_atdca<<<B * N, 64, 0, stream>>>(x, g1, b1, wq_w, wq_b, ca_scale, kn, vv, acc, tk_id);
    k_qkv<<<B * N / 8, 256, 0, stream>>>(t_buf, g1, b1, wqkv_w, wqkv_b, qkv);
    k_sort_count<<<dim3(128, B), 128, 0, stream>>>(tk_id, ccnt);
    k_sort_scan<<<B, 128, 0, stream>>>(ccnt);
    k_sort_scatter<<<dim3(128, B), 128, 0, stream>>>(tk_id, ccnt, sidx);
    k_attn<<<dim3(NG, HEADS, B), 256, 0, stream>>>(qkv, sidx, o_bufp);
    k_proj<<<B * N / 8, 192, 0, stream>>>(o_bufp, proj_w, proj_b, acc);
    k_fc1<<<B * N / 8, 256, 0, stream>>>(t_buf, g2, b2v, fc1_w, fc1_b, tk_id, tdf, hcat);
    k_conv<<<B * N, 256, 0, stream>>>(hcat, dw_w, dw_b, convsum);
    k_fc2_out<<<B * N / 8, 192, 0, stream>>>(convsum, fc2_w, fc2_b, g3, b3, acc, out);
}

// Round 4
// 1302.019 us; speedup vs baseline: 2.3037x; 2.3037x over previous
//
#include <hip/hip_runtime.h>
#include <hip/hip_bf16.h>
#include <math.h>

using bf16 = __hip_bfloat16;

static constexpr int B = 2, C = 192, Hh = 128, Ww = 128, N = Hh * Ww;
static constexpr int M = 128, RD = 10, GS = 256, NG = N / GS;
static constexpr int HEADS = 4, HD = C / HEADS;                      // 48
static constexpr int TDF = 16, HID = 4 * C, HIDT = HID + TDF;        // 768, 784
static constexpr int TC3 = 3 * C;                                    // 576
static constexpr float LOG_M = 4.852030263919617f;                   // ln(128)

typedef __attribute__((ext_vector_type(8))) short bf16x8;
typedef __attribute__((ext_vector_type(4))) float f32x4;

__device__ __forceinline__ float b2f(bf16 v) { return __bfloat162float(v); }
__device__ __forceinline__ bf16 f2b(float v) { return __float2bfloat16(v); }
__device__ __forceinline__ float bits2f(unsigned short u) { return __uint_as_float(((unsigned)u) << 16); }
__device__ __forceinline__ unsigned short f2bits(float f) {
    union { bf16 h; unsigned short u; } cv; cv.h = f2b(f); return cv.u;
}
__device__ __forceinline__ float gelu_exact(float v) {
    return 0.5f * v * (1.0f + erff(v * 0.70710678118654752f));
}

// ---------- K0: token-dict precompute: kn, v, td_feat ----------
__global__ void k_precompute(const float* td, const float* wk_w, const float* wk_b,
                             const float* wv_w, const float* wv_b,
                             const float* fc_td_w, const float* fc_td_b,
                             float* kn, float* vv, float* tdf) {
    int m = blockIdx.x;
    int lane = threadIdx.x;      // 64
    __shared__ float trow[C];
    for (int ch = lane; ch < C; ch += 64) trow[ch] = td[m * C + ch];
    __syncthreads();
    __shared__ float ks[RD];
    __shared__ float inv_s;
    if (lane < RD) {
        float s = wk_b[lane];
        for (int ch = 0; ch < C; ++ch) s += trow[ch] * wk_w[ch * RD + lane];
        ks[lane] = s;
    }
    __syncthreads();
    if (lane == 0) {
        float ss = 0.f;
        for (int r = 0; r < RD; ++r) ss += ks[r] * ks[r];
        inv_s = 1.0f / fmaxf(sqrtf(ss), 1e-12f);
    }
    __syncthreads();
    if (lane < RD) kn[m * RD + lane] = ks[lane] * inv_s;
    for (int c0 = 0; c0 < 3; ++c0) {
        int co = lane + 64 * c0;
        float s = wv_b[co];
        for (int ch = 0; ch < C; ++ch) s += trow[ch] * wv_w[ch * C + co];
        vv[m * C + co] = s;
    }
    if (lane < TDF) {
        float s = fc_td_b[lane];
        for (int ch = 0; ch < C; ++ch) s += trow[ch] * fc_td_w[ch * TDF + lane];
        tdf[m * TDF + lane] = s;
    }
}

// ---------- K1: LN core via LDS transpose: t(bf16), xn32(fp32), acc=x ----------
__global__ void __launch_bounds__(256) k_ln(const float* x, bf16* t, float* xn32, float* acc) {
    __shared__ float Xs[64 * 193];
    __shared__ float mu_s[64], rs_s[64];
    int tid = threadIdx.x;
    int m0 = blockIdx.x * 64;
    int b = m0 / N, i0 = m0 % N;                 // tile never crosses batch (N%64==0)
    for (int e = tid; e < 192 * 64; e += 256) {
        int ch = e >> 6, ii = e & 63;
        Xs[ii * 193 + ch] = x[((size_t)b * C + ch) * N + i0 + ii];
    }
    __syncthreads();
    {
        int tok = tid >> 2, part = tid & 3;
        float s = 0.f, ss = 0.f;
        for (int ch = part * 48; ch < part * 48 + 48; ++ch) {
            float v = Xs[tok * 193 + ch]; s += v; ss += v * v;
        }
        s += __shfl_xor(s, 1); ss += __shfl_xor(ss, 1);
        s += __shfl_xor(s, 2); ss += __shfl_xor(ss, 2);
        if (part == 0) {
            float mu = s / C;
            mu_s[tok] = mu;
            rs_s[tok] = rsqrtf(ss / C - mu * mu + 1e-5f);
        }
    }
    __syncthreads();
    for (int e = tid; e < 64 * 192; e += 256) {
        int ii = e / 192, ch = e % 192;
        float v = Xs[ii * 193 + ch];
        float xn = (v - mu_s[ii]) * rs_s[ii];
        size_t g = (size_t)(m0 + ii);
        t[g * C + ch] = f2b(xn);
        xn32[g * C + ch] = xn;
        acc[g * C + ch] = v;                     // shortcut
    }
}

// ---------- K2: ATD_CA: q -> cosine sim -> softmax+argmax -> +p@v into acc ----------
__global__ void __launch_bounds__(256) k_atdca(const float* xn32, const float* g1, const float* b1,
                        const float* wq_w, const float* wq_b, const float* ca_scale,
                        const float* kn, const float* vv,
                        float* acc, int* tk_id) {
    int t0 = blockIdx.x * 4;
    int w = threadIdx.x >> 6, lane = threadIdx.x & 63;
    int g = t0 + w;
    __shared__ float p_s[4][M];
    float xn[3];
    #pragma unroll
    for (int k = 0; k < 3; ++k) {
        int ch = lane + 64 * k;
        xn[k] = xn32[(size_t)g * C + ch] * g1[ch] + b1[ch];
    }
    float q[RD];
    #pragma unroll
    for (int r = 0; r < RD; ++r) {
        float p = 0.f;
        #pragma unroll
        for (int k = 0; k < 3; ++k) { int ch = lane + 64 * k; p += xn[k] * wq_w[ch * RD + r]; }
        for (int mk = 32; mk >= 1; mk >>= 1) p += __shfl_xor(p, mk);
        q[r] = p + wq_b[r];
    }
    float ssn = 0.f;
    #pragma unroll
    for (int r = 0; r < RD; ++r) ssn += q[r] * q[r];
    float invq = 1.0f / fmaxf(sqrtf(ssn), 1e-12f);
    float s0 = 0.f, s1 = 0.f;
    #pragma unroll
    for (int r = 0; r < RD; ++r) {
        float qr = q[r] * invq;
        s0 += qr * kn[lane * RD + r];
        s1 += qr * kn[(lane + 64) * RD + r];
    }
    float mv; int mi;
    if (s1 > s0) { mv = s1; mi = lane + 64; } else { mv = s0; mi = lane; }
    for (int mk = 32; mk >= 1; mk >>= 1) {
        float ov = __shfl_xor(mv, mk); int oi = __shfl_xor(mi, mk);
        if (ov > mv || (ov == mv && oi < mi)) { mv = ov; mi = oi; }
    }
    float cs = ca_scale[0]; cs = fminf(fmaxf(cs, 0.0f), 3.0f);
    float scale = 1.0f + cs * LOG_M;
    float e0 = expf((s0 - mv) * scale), e1 = expf((s1 - mv) * scale);
    float sum = e0 + e1;
    for (int mk = 32; mk >= 1; mk >>= 1) sum += __shfl_xor(sum, mk);
    float invs = 1.0f / sum;
    p_s[w][lane] = e0 * invs;
    p_s[w][lane + 64] = e1 * invs;
    if (lane == 0) tk_id[g] = mi;
    __syncthreads();
    for (int e = threadIdx.x; e < 4 * C; e += 256) {
        int tok = e / C, ch = e % C;
        float a = 0.f;
        const float* vp = vv + ch;
        #pragma unroll 4
        for (int m = 0; m < M; ++m) a += p_s[tok][m] * vp[m * C];
        acc[(size_t)(t0 + tok) * C + ch] += a;
    }
}

// ---------- MFMA GEMM, K=192: modes 0=store bf16, 1=gelu+store bf16, 2=accumulate fp32 ----------
template<int NOUT, int OUTLD, int MODE, bool HASGAIN>
__global__ void __launch_bounds__(256) k_gemm192(const bf16* Abuf, const float* gain, const float* beta,
                                                 const float* W, const float* bias,
                                                 bf16* outb, float* outf) {
    __shared__ __align__(16) short As[64 * 200];
    __shared__ __align__(16) short Bs[64 * 200];
    int tid = threadIdx.x;
    int m0 = blockIdx.x * 64;
    int n0 = blockIdx.y * 64;
    // stage A (64 tokens x 192)
    for (int e = tid; e < 64 * 24; e += 256) {
        int m = e / 24, kc = (e % 24) * 8;
        uint4 raw = *(const uint4*)(Abuf + (size_t)(m0 + m) * C + kc);
        if (HASGAIN) {
            unsigned short* u = (unsigned short*)&raw;
            unsigned short o[8];
            #pragma unroll
            for (int j = 0; j < 8; ++j) o[j] = f2bits(bits2f(u[j]) * gain[kc + j] + beta[kc + j]);
            *(uint4*)&As[m * 200 + kc] = *(uint4*)o;
        } else {
            *(uint4*)&As[m * 200 + kc] = raw;
        }
    }
    // stage B transposed: Bs[n][k]
    for (int e = tid; e < 64 * 24; e += 256) {
        int n = e / 24, kc = (e % 24) * 8;
        unsigned short o[8];
        #pragma unroll
        for (int j = 0; j < 8; ++j) o[j] = f2bits(W[(size_t)(kc + j) * NOUT + n0 + n]);
        *(uint4*)&Bs[n * 200 + kc] = *(uint4*)o;
    }
    __syncthreads();
    int w = tid >> 6, lane = tid & 63;
    int wm = (w >> 1) * 32, wn = (w & 1) * 32;
    int lr = lane & 15, lk = (lane >> 4) * 8;
    f32x4 acc00 = {0.f,0.f,0.f,0.f}, acc01 = acc00, acc10 = acc00, acc11 = acc00;
    #pragma unroll
    for (int ks = 0; ks < 6; ++ks) {
        int k0 = ks * 32 + lk;
        bf16x8 a0 = *(bf16x8*)&As[(wm + lr) * 200 + k0];
        bf16x8 a1 = *(bf16x8*)&As[(wm + 16 + lr) * 200 + k0];
        bf16x8 b0 = *(bf16x8*)&Bs[(wn + lr) * 200 + k0];
        bf16x8 b1 = *(bf16x8*)&Bs[(wn + 16 + lr) * 200 + k0];
        acc00 = __builtin_amdgcn_mfma_f32_16x16x32_bf16(a0, b0, acc00, 0, 0, 0);
        acc01 = __builtin_amdgcn_mfma_f32_16x16x32_bf16(a0, b1, acc01, 0, 0, 0);
        acc10 = __builtin_amdgcn_mfma_f32_16x16x32_bf16(a1, b0, acc10, 0, 0, 0);
        acc11 = __builtin_amdgcn_mfma_f32_16x16x32_bf16(a1, b1, acc11, 0, 0, 0);
    }
    int rbase = (lane >> 4) * 4;
    f32x4 accs[2][2] = {{acc00, acc01}, {acc10, acc11}};
    #pragma unroll
    for (int mt = 0; mt < 2; ++mt) {
        #pragma unroll
        for (int nt = 0; nt < 2; ++nt) {
            int co = n0 + wn + nt * 16 + lr;
            float bv = bias[co];
            #pragma unroll
            for (int r = 0; r < 4; ++r) {
                int tok = m0 + wm + mt * 16 + rbase + r;
                float v = accs[mt][nt][r] + bv;
                if (MODE == 0) outb[(size_t)tok * OUTLD + co] = f2b(v);
                else if (MODE == 1) outb[(size_t)tok * OUTLD + co] = f2b(gelu_exact(v));
                else outf[(size_t)tok * OUTLD + co] += v;
            }
        }
    }
}

// ---------- Stable counting sort by tk_id ----------
__global__ void k_sort_count(const int* tk_id, int* chunk_cnt) {
    int c = blockIdx.x, b = blockIdx.y;
    int tid = threadIdx.x;               // 128
    __shared__ int cnt[M];
    cnt[tid] = 0;
    __syncthreads();
    atomicAdd(&cnt[tk_id[b * N + c * 128 + tid]], 1);
    __syncthreads();
    chunk_cnt[(b * 128 + c) * M + tid] = cnt[tid];
}

__global__ void k_sort_scan(int* chunk_cnt) {
    int b = blockIdx.x;
    int k = threadIdx.x;                 // 128 keys
    int tot = 0;
    for (int c = 0; c < 128; ++c) tot += chunk_cnt[(b * 128 + c) * M + k];
    __shared__ int totals[M];
    __shared__ int base[M];
    totals[k] = tot;
    __syncthreads();
    if (k == 0) {
        int run = 0;
        for (int kk = 0; kk < M; ++kk) { base[kk] = run; run += totals[kk]; }
    }
    __syncthreads();
    int run = base[k];
    for (int c = 0; c < 128; ++c) {
        int v = chunk_cnt[(b * 128 + c) * M + k];
        chunk_cnt[(b * 128 + c) * M + k] = run;
        run += v;
    }
}

__global__ void k_sort_scatter(const int* tk_id, const int* chunk_cnt, int* sort_idx) {
    int c = blockIdx.x, b = blockIdx.y;
    int k = threadIdx.x;
    __shared__ int keys[128];
    keys[k] = tk_id[b * N + c * 128 + k];
    __syncthreads();
    int off = chunk_cnt[(b * 128 + c) * M + k];
    for (int j = 0; j < 128; ++j) {
        if (keys[j] == k) sort_idx[b * N + off++] = c * 128 + j;
    }
}

// ---------- grouped self-attention ----------
__global__ void __launch_bounds__(256) k_attn(const bf16* qkv, const int* sort_idx, bf16* o_buf) {
    int g = blockIdx.x, hh = blockIdx.y, b = blockIdx.z;
    int tid = threadIdx.x;               // 256 = GS
    __shared__ int sidx[GS];
    __shared__ bf16 Kl[GS][HD];
    __shared__ bf16 Vl[GS][HD];
    sidx[tid] = sort_idx[b * N + g * GS + tid];
    __syncthreads();
    for (int idx = tid; idx < GS * HD; idx += 256) {
        int row = idx / HD, d = idx % HD;
        size_t base = ((size_t)(b * N + sidx[row])) * TC3 + hh * HD + d;
        Kl[row][d] = qkv[base + C];
        Vl[row][d] = qkv[base + 2 * C];
    }
    __syncthreads();
    float qv[HD];
    {
        size_t base = ((size_t)(b * N + sidx[tid])) * TC3 + hh * HD;
        #pragma unroll
        for (int d = 0; d < HD; ++d) qv[d] = b2f(qkv[base + d]) * 0.14433756729740643f;
    }
    float mmax = -1e30f, lsum = 0.f;
    for (int kk = 0; kk < GS; ++kk) {
        float sd = 0.f;
        #pragma unroll
        for (int d = 0; d < HD; ++d) sd += qv[d] * b2f(Kl[kk][d]);
        if (sd > mmax) { lsum = lsum * expf(mmax - sd) + 1.0f; mmax = sd; }
        else lsum += expf(sd - mmax);
    }
    float ov[HD];
    #pragma unroll
    for (int d = 0; d < HD; ++d) ov[d] = 0.f;
    for (int kk = 0; kk < GS; ++kk) {
        float sd = 0.f;
        #pragma unroll
        for (int d = 0; d < HD; ++d) sd += qv[d] * b2f(Kl[kk][d]);
        float p = expf(sd - mmax);
        #pragma unroll
        for (int d = 0; d < HD; ++d) ov[d] += p * b2f(Vl[kk][d]);
    }
    float inv = 1.0f / lsum;
    size_t obase = ((size_t)(b * N + sidx[tid])) * C + hh * HD;
    #pragma unroll
    for (int d = 0; d < HD; ++d) o_buf[obase + d] = f2b(ov[d] * inv);
}

// ---------- td feature gather into hcat tail columns ----------
__global__ void k_tdfill(const int* tk_id, const float* tdf, bf16* hcat) {
    int idx = blockIdx.x * 256 + threadIdx.x;
    if (idx >= B * N * TDF) return;
    int tok = idx >> 4, f = idx & 15;
    hcat[(size_t)tok * HIDT + HID + f] = f2b(tdf[tk_id[tok] * TDF + f]);
}

// ---------- depthwise 5x5 conv, tiled: 16x16 spatial x 16 ch ----------
__global__ void __launch_bounds__(256) k_conv(const bf16* hcat, const float* dw_w, const float* dw_b,
                                              bf16* convsum) {
    int st = blockIdx.x;                 // 64 spatial tiles
    int c16 = blockIdx.y;                // 49 channel chunks
    int b = blockIdx.z;
    int ty = (st >> 3) * 16, tx = (st & 7) * 16;
    int tid = threadIdx.x;
    __shared__ __align__(16) unsigned short Hs[400 * 16];
    __shared__ float Ws[16 * 25];
    __shared__ float Wb[16];
    for (int e = tid; e < 400; e += 256) {   // FIX: was `if (tid < 400)` with 256 threads
        int ch = e / 25, tap = e % 25;
        Ws[e] = dw_w[(size_t)(c16 * 16 + ch) * 25 + tap];
    }
    if (tid < 16) Wb[tid] = dw_b[c16 * 16 + tid];
    for (int e = tid; e < 800; e += 256) {
        int pos = e >> 1, cc = e & 1;
        int py = pos / 20, px = pos % 20;
        int gy = ty + py - 2, gx = tx + px - 2;
        uint4 v = {0u, 0u, 0u, 0u};
        if (gy >= 0 && gy < Hh && gx >= 0 && gx < Ww)
            v = *(const uint4*)(hcat + ((size_t)b * N + gy * Ww + gx) * HIDT + c16 * 16 + cc * 8);
        *(uint4*)&Hs[pos * 16 + cc * 8] = v;
    }
    __syncthreads();
    #pragma unroll
    for (int j = 0; j < 2; ++j) {
        int item = tid + 256 * j;        // 512 = 256 pos x 2 cc
        int pos = item >> 1, cc = item & 1;
        int ly = pos >> 4, lx = pos & 15;
        float a8[8];
        #pragma unroll
        for (int ch = 0; ch < 8; ++ch) a8[ch] = 0.f;
        #pragma unroll
        for (int ky = 0; ky < 5; ++ky) {
            #pragma unroll
            for (int kx = 0; kx < 5; ++kx) {
                uint4 hv = *(uint4*)&Hs[((ly + ky) * 20 + lx + kx) * 16 + cc * 8];
                unsigned short* hu = (unsigned short*)&hv;
                #pragma unroll
                for (int ch = 0; ch < 8; ++ch)
                    a8[ch] += bits2f(hu[ch]) * Ws[(cc * 8 + ch) * 25 + ky * 5 + kx];
            }
        }
        uint4 cv4 = *(uint4*)&Hs[((ly + 2) * 20 + lx + 2) * 16 + cc * 8];
        unsigned short* cu = (unsigned short*)&cv4;
        unsigned short ow[8];
        #pragma unroll
        for (int ch = 0; ch < 8; ++ch)
            ow[ch] = f2bits(bits2f(cu[ch]) + gelu_exact(a8[ch] + Wb[cc * 8 + ch]));
        int gy = ty + ly, gx = tx + lx;
        *(uint4*)(convsum + ((size_t)b * N + gy * Ww + gx) * HIDT + c16 * 16 + cc * 8) = *(uint4*)ow;
    }
}

// ---------- fc2 (K=784) MFMA + bias + LN3 + residual + transposed store ----------
__global__ void __launch_bounds__(256) k_fc2ln(const bf16* convsum, const float* W,
                                               const float* bias, const float* g3, const float* b3,
                                               const float* accres, float* out) {
    __shared__ __align__(16) short As[64 * 72];
    __shared__ __align__(16) short Bs[192 * 72];
    int tid = threadIdx.x;
    int m0 = blockIdx.x * 64;
    int w = tid >> 6, lane = tid & 63;
    int lr = lane & 15, lk = (lane >> 4) * 8;
    f32x4 acc[12];
    #pragma unroll
    for (int nt = 0; nt < 12; ++nt) acc[nt] = (f32x4){0.f, 0.f, 0.f, 0.f};
    for (int kc = 0; kc < 13; ++kc) {
        int kb = kc * 64;
        if (kb + 64 <= HIDT) {
            for (int e = tid; e < 512; e += 256) {
                int m = e >> 3, k8 = (e & 7) * 8;
                *(uint4*)&As[m * 72 + k8] = *(const uint4*)(convsum + (size_t)(m0 + m) * HIDT + kb + k8);
            }
        } else {
            for (int e = tid; e < 512; e += 256) {
                int m = e >> 3, k8 = (e & 7) * 8;
                unsigned short tmp[8];
                #pragma unroll
                for (int jj = 0; jj < 8; ++jj) {
                    int k = kb + k8 + jj;
                    union { bf16 h; unsigned short u; } cv; cv.u = 0;
                    if (k < HIDT) cv.h = convsum[(size_t)(m0 + m) * HIDT + k];
                    tmp[jj] = cv.u;
                }
                *(uint4*)&As[m * 72 + k8] = *(uint4*)tmp;
            }
        }
        for (int e = tid; e < 1536; e += 256) {
            int n = e >> 3, k8 = (e & 7) * 8;
            unsigned short tmp[8];
            #pragma unroll
            for (int jj = 0; jj < 8; ++jj) {
                int k = kb + k8 + jj;
                tmp[jj] = (k < HIDT) ? f2bits(W[(size_t)k * C + n]) : (unsigned short)0;
            }
            *(uint4*)&Bs[n * 72 + k8] = *(uint4*)tmp;
        }
        __syncthreads();
        #pragma unroll
        for (int ks = 0; ks < 2; ++ks) {
            int k0 = ks * 32 + lk;
            bf16x8 a = *(bf16x8*)&As[(w * 16 + lr) * 72 + k0];
            #pragma unroll
            for (int nt = 0; nt < 12; ++nt) {
                bf16x8 bfr = *(bf16x8*)&Bs[(nt * 16 + lr) * 72 + k0];
                acc[nt] = __builtin_amdgcn_mfma_f32_16x16x32_bf16(a, bfr, acc[nt], 0, 0, 0);
            }
        }
        __syncthreads();
    }
    // bias
    #pragma unroll
    for (int nt = 0; nt < 12; ++nt) {
        float bv = bias[nt * 16 + lr];
        #pragma unroll
        for (int r = 0; r < 4; ++r) acc[nt][r] += bv;
    }
    // LN per token row + residual + transposed store
    #pragma unroll
    for (int r = 0; r < 4; ++r) {
        float s = 0.f, ss = 0.f;
        #pragma unroll
        for (int nt = 0; nt < 12; ++nt) { float v = acc[nt][r]; s += v; ss += v * v; }
        s += __shfl_xor(s, 1); ss += __shfl_xor(ss, 1);
        s += __shfl_xor(s, 2); ss += __shfl_xor(ss, 2);
        s += __shfl_xor(s, 4); ss += __shfl_xor(ss, 4);
        s += __shfl_xor(s, 8); ss += __shfl_xor(ss, 8);
        float mu = s / C;
        float rstd = rsqrtf(ss / C - mu * mu + 1e-5f);
        int tok = m0 + w * 16 + (lane >> 4) * 4 + r;
        int b = tok / N, i = tok % N;
        #pragma unroll
        for (int nt = 0; nt < 12; ++nt) {
            int c = nt * 16 + lr;
            float o = accres[(size_t)tok * C + c] + (acc[nt][r] - mu) * rstd * g3[c] + b3[c];
            out[((size_t)b * C + c) * N + i] = o;
        }
    }
}

__global__ void k_sentinel(float* out, int nelem) {
    int i = blockIdx.x * blockDim.x + threadIdx.x;
    if (i < nelem) out[i] = 1234.0f;
}

extern "C" void kernel_launch(void* const* d_in, const int* in_sizes, int n_in,
                              void* d_out, int out_size, void* d_ws, size_t ws_size,
                              hipStream_t stream) {
    const float* x        = (const float*)d_in[0];
    const float* td       = (const float*)d_in[2];
    const float* g1       = (const float*)d_in[3];
    const float* b1       = (const float*)d_in[4];
    const float* g2       = (const float*)d_in[5];
    const float* b2v      = (const float*)d_in[6];
    const float* g3       = (const float*)d_in[7];
    const float* b3       = (const float*)d_in[8];
    const float* wq_w     = (const float*)d_in[9];
    const float* wq_b     = (const float*)d_in[10];
    const float* wk_w     = (const float*)d_in[11];
    const float* wk_b     = (const float*)d_in[12];
    const float* wv_w     = (const float*)d_in[13];
    const float* wv_b     = (const float*)d_in[14];
    const float* ca_scale = (const float*)d_in[15];
    const float* wqkv_w   = (const float*)d_in[16];
    const float* wqkv_b   = (const float*)d_in[17];
    const float* proj_w   = (const float*)d_in[18];
    const float* proj_b   = (const float*)d_in[19];
    const float* fc_td_w  = (const float*)d_in[20];
    const float* fc_td_b  = (const float*)d_in[21];
    const float* fc1_w    = (const float*)d_in[22];
    const float* fc1_b    = (const float*)d_in[23];
    const float* dw_w     = (const float*)d_in[24];
    const float* dw_b     = (const float*)d_in[25];
    const float* fc2_w    = (const float*)d_in[26];
    const float* fc2_b    = (const float*)d_in[27];
    float* out = (float*)d_out;

    char* ws = (char*)d_ws;
    size_t off = 0;
    auto alloc = [&](size_t bytes) { size_t o = off; off += (bytes + 255) & ~(size_t)255; return o; };
    size_t o_t    = alloc((size_t)B * N * C * 2);
    size_t o_xn32 = alloc((size_t)B * N * C * 4);
    size_t o_acc  = alloc((size_t)B * N * C * 4);
    size_t o_qkv  = alloc((size_t)B * N * TC3 * 2);
    size_t o_obuf = alloc((size_t)B * N * C * 2);
    size_t o_hcat = alloc((size_t)B * N * HIDT * 2);
    size_t o_conv = alloc((size_t)B * N * HIDT * 2);
    size_t o_kn   = alloc((size_t)M * RD * 4);
    size_t o_vv   = alloc((size_t)M * C * 4);
    size_t o_tdf  = alloc((size_t)M * TDF * 4);
    size_t o_tk   = alloc((size_t)B * N * 4);
    size_t o_sidx = alloc((size_t)B * N * 4);
    size_t o_ccnt = alloc((size_t)B * 128 * M * 4);

    if (ws_size < off) {
        k_sentinel<<<(out_size + 255) / 256, 256, 0, stream>>>(out, out_size);
        return;
    }

    bf16*  t_buf   = (bf16*)(ws + o_t);
    float* xn32    = (float*)(ws + o_xn32);
    float* acc     = (float*)(ws + o_acc);
    bf16*  qkv     = (bf16*)(ws + o_qkv);
    bf16*  o_bufp  = (bf16*)(ws + o_obuf);
    bf16*  hcat    = (bf16*)(ws + o_hcat);
    bf16*  convsum = (bf16*)(ws + o_conv);
    float* kn      = (float*)(ws + o_kn);
    float* vv      = (float*)(ws + o_vv);
    float* tdf     = (float*)(ws + o_tdf);
    int*   tk_id   = (int*)(ws + o_tk);
    int*   sidx    = (int*)(ws + o_sidx);
    int*   ccnt    = (int*)(ws + o_ccnt);

    k_precompute<<<M, 64, 0, stream>>>(td, wk_w, wk_b, wv_w, wv_b, fc_td_w, fc_td_b, kn, vv, tdf);
    k_ln<<<B * N / 64, 256, 0, stream>>>(x, t_buf, xn32, acc);
    k_atdca<<<B * N / 4, 256, 0, stream>>>(xn32, g1, b1, wq_w, wq_b, ca_scale, kn, vv, acc, tk_id);
    k_gemm192<TC3, TC3, 0, true><<<dim3(B * N / 64, TC3 / 64), 256, 0, stream>>>(
        t_buf, g1, b1, wqkv_w, wqkv_b, qkv, nullptr);
    k_sort_count<<<dim3(128, B), 128, 0, stream>>>(tk_id, ccnt);
    k_sort_scan<<<B, 128, 0, stream>>>(ccnt);
    k_sort_scatter<<<dim3(128, B), 128, 0, stream>>>(tk_id, ccnt, sidx);
    k_attn<<<dim3(NG, HEADS, B), 256, 0, stream>>>(qkv, sidx, o_bufp);
    k_gemm192<C, C, 2, false><<<dim3(B * N / 64, C / 64), 256, 0, stream>>>(
        o_bufp, nullptr, nullptr, proj_w, proj_b, nullptr, acc);
    k_gemm192<HID, HIDT, 1, true><<<dim3(B * N / 64, HID / 64), 256, 0, stream>>>(
        t_buf, g2, b2v, fc1_w, fc1_b, hcat, nullptr);
    k_tdfill<<<(B * N * TDF + 255) / 256, 256, 0, stream>>>(tk_id, tdf, hcat);
    k_conv<<<dim3(64, 49, B), 256, 0, stream>>>(hcat, dw_w, dw_b, convsum);
    k_fc2ln<<<B * N / 64, 256, 0, stream>>>(convsum, fc2_w, fc2_b, g3, b3, acc, out);
}

// Round 5
// 635.453 us; speedup vs baseline: 4.7202x; 2.0490x over previous
//
#include <hip/hip_runtime.h>
#include <hip/hip_bf16.h>
#include <math.h>

using bf16 = __hip_bfloat16;

static constexpr int B = 2, C = 192, Hh = 128, Ww = 128, N = Hh * Ww;
static constexpr int M = 128, RD = 10, GS = 256, NG = N / GS;
static constexpr int HEADS = 4, HD = C / HEADS;                      // 48
static constexpr int TDF = 16, HID = 4 * C, HIDT = HID + TDF;        // 768, 784
static constexpr int TC3 = 3 * C;                                    // 576
static constexpr float LOG_M = 4.852030263919617f;                   // ln(128)
static constexpr float ATT_SCALE = 0.14433756729740643f;             // 48^-0.5

typedef __attribute__((ext_vector_type(8))) short bf16x8;
typedef __attribute__((ext_vector_type(4))) float f32x4;

__device__ __forceinline__ float b2f(bf16 v) { return __bfloat162float(v); }
__device__ __forceinline__ bf16 f2b(float v) { return __float2bfloat16(v); }
__device__ __forceinline__ float bits2f(unsigned short u) { return __uint_as_float(((unsigned)u) << 16); }
__device__ __forceinline__ unsigned short f2bits(float f) {
    union { bf16 h; unsigned short u; } cv; cv.h = f2b(f); return cv.u;
}
__device__ __forceinline__ float gelu_exact(float v) {
    return 0.5f * v * (1.0f + erff(v * 0.70710678118654752f));
}

// ---------- weight transpose+convert: in[K][Nn] f32 -> out[Nn][K] bf16 ----------
__global__ void __launch_bounds__(256) k_wtrans(const float* in, bf16* out, int K, int Nn) {
    __shared__ float T[64][65];
    int n0 = blockIdx.x * 64, k0 = blockIdx.y * 64;
    int tid = threadIdx.x;
    for (int e = tid; e < 4096; e += 256) {
        int kk = e >> 6, nn = e & 63;
        if (k0 + kk < K) T[kk][nn] = in[(size_t)(k0 + kk) * Nn + n0 + nn];
    }
    __syncthreads();
    for (int e = tid; e < 4096; e += 256) {
        int nn = e >> 6, kk = e & 63;
        if (k0 + kk < K) out[(size_t)(n0 + nn) * K + k0 + kk] = f2b(T[kk][nn]);
    }
}

// ---------- K0: token-dict precompute: kn, v, td_feat ----------
__global__ void k_precompute(const float* td, const float* wk_w, const float* wk_b,
                             const float* wv_w, const float* wv_b,
                             const float* fc_td_w, const float* fc_td_b,
                             float* kn, float* vv, float* tdf) {
    int m = blockIdx.x;
    int lane = threadIdx.x;      // 64
    __shared__ float trow[C];
    for (int ch = lane; ch < C; ch += 64) trow[ch] = td[m * C + ch];
    __syncthreads();
    __shared__ float ks[RD];
    __shared__ float inv_s;
    if (lane < RD) {
        float s = wk_b[lane];
        for (int ch = 0; ch < C; ++ch) s += trow[ch] * wk_w[ch * RD + lane];
        ks[lane] = s;
    }
    __syncthreads();
    if (lane == 0) {
        float ss = 0.f;
        for (int r = 0; r < RD; ++r) ss += ks[r] * ks[r];
        inv_s = 1.0f / fmaxf(sqrtf(ss), 1e-12f);
    }
    __syncthreads();
    if (lane < RD) kn[m * RD + lane] = ks[lane] * inv_s;
    for (int c0 = 0; c0 < 3; ++c0) {
        int co = lane + 64 * c0;
        float s = wv_b[co];
        for (int ch = 0; ch < C; ++ch) s += trow[ch] * wv_w[ch * C + co];
        vv[m * C + co] = s;
    }
    if (lane < TDF) {
        float s = fc_td_b[lane];
        for (int ch = 0; ch < C; ++ch) s += trow[ch] * fc_td_w[ch * TDF + lane];
        tdf[m * TDF + lane] = s;
    }
}

// ---------- K1: LN core via LDS transpose: t(bf16), xn32(fp32), acc=x ----------
__global__ void __launch_bounds__(256) k_ln(const float* x, bf16* t, float* xn32, float* acc) {
    __shared__ float Xs[64 * 193];
    __shared__ float mu_s[64], rs_s[64];
    int tid = threadIdx.x;
    int m0 = blockIdx.x * 64;
    int b = m0 / N, i0 = m0 % N;
    for (int e = tid; e < 192 * 64; e += 256) {
        int ch = e >> 6, ii = e & 63;
        Xs[ii * 193 + ch] = x[((size_t)b * C + ch) * N + i0 + ii];
    }
    __syncthreads();
    {
        int tok = tid >> 2, part = tid & 3;
        float s = 0.f, ss = 0.f;
        for (int ch = part * 48; ch < part * 48 + 48; ++ch) {
            float v = Xs[tok * 193 + ch]; s += v; ss += v * v;
        }
        s += __shfl_xor(s, 1); ss += __shfl_xor(ss, 1);
        s += __shfl_xor(s, 2); ss += __shfl_xor(ss, 2);
        if (part == 0) {
            float mu = s / C;
            mu_s[tok] = mu;
            rs_s[tok] = rsqrtf(ss / C - mu * mu + 1e-5f);
        }
    }
    __syncthreads();
    for (int e = tid; e < 64 * 192; e += 256) {
        int ii = e / 192, ch = e % 192;
        float v = Xs[ii * 193 + ch];
        float xn = (v - mu_s[ii]) * rs_s[ii];
        size_t g = (size_t)(m0 + ii);
        t[g * C + ch] = f2b(xn);
        xn32[g * C + ch] = xn;
        acc[g * C + ch] = v;
    }
}

// ---------- K2: ATD_CA ----------
__global__ void __launch_bounds__(256) k_atdca(const float* xn32, const float* g1, const float* b1,
                        const float* wq_w, const float* wq_b, const float* ca_scale,
                        const float* kn, const float* vv,
                        float* acc, int* tk_id) {
    int t0 = blockIdx.x * 4;
    int w = threadIdx.x >> 6, lane = threadIdx.x & 63;
    int g = t0 + w;
    __shared__ float p_s[4][M];
    float xn[3];
    #pragma unroll
    for (int k = 0; k < 3; ++k) {
        int ch = lane + 64 * k;
        xn[k] = xn32[(size_t)g * C + ch] * g1[ch] + b1[ch];
    }
    float q[RD];
    #pragma unroll
    for (int r = 0; r < RD; ++r) {
        float p = 0.f;
        #pragma unroll
        for (int k = 0; k < 3; ++k) { int ch = lane + 64 * k; p += xn[k] * wq_w[ch * RD + r]; }
        for (int mk = 32; mk >= 1; mk >>= 1) p += __shfl_xor(p, mk);
        q[r] = p + wq_b[r];
    }
    float ssn = 0.f;
    #pragma unroll
    for (int r = 0; r < RD; ++r) ssn += q[r] * q[r];
    float invq = 1.0f / fmaxf(sqrtf(ssn), 1e-12f);
    float s0 = 0.f, s1 = 0.f;
    #pragma unroll
    for (int r = 0; r < RD; ++r) {
        float qr = q[r] * invq;
        s0 += qr * kn[lane * RD + r];
        s1 += qr * kn[(lane + 64) * RD + r];
    }
    float mv; int mi;
    if (s1 > s0) { mv = s1; mi = lane + 64; } else { mv = s0; mi = lane; }
    for (int mk = 32; mk >= 1; mk >>= 1) {
        float ov = __shfl_xor(mv, mk); int oi = __shfl_xor(mi, mk);
        if (ov > mv || (ov == mv && oi < mi)) { mv = ov; mi = oi; }
    }
    float cs = ca_scale[0]; cs = fminf(fmaxf(cs, 0.0f), 3.0f);
    float scale = 1.0f + cs * LOG_M;
    float e0 = expf((s0 - mv) * scale), e1 = expf((s1 - mv) * scale);
    float sum = e0 + e1;
    for (int mk = 32; mk >= 1; mk >>= 1) sum += __shfl_xor(sum, mk);
    float invs = 1.0f / sum;
    p_s[w][lane] = e0 * invs;
    p_s[w][lane + 64] = e1 * invs;
    if (lane == 0) tk_id[g] = mi;
    __syncthreads();
    for (int e = threadIdx.x; e < 4 * C; e += 256) {
        int tok = e / C, ch = e % C;
        float a = 0.f;
        const float* vp = vv + ch;
        #pragma unroll 4
        for (int m = 0; m < M; ++m) a += p_s[tok][m] * vp[m * C];
        acc[(size_t)(t0 + tok) * C + ch] += a;
    }
}

// ---------- MFMA GEMM, K=192, Wt = transposed bf16 [NOUT][192] ----------
template<int NOUT, int OUTLD, int MODE, bool HASGAIN>
__global__ void __launch_bounds__(256) k_gemm192(const bf16* Abuf, const float* gain, const float* beta,
                                                 const bf16* Wt, const float* bias,
                                                 bf16* outb, float* outf) {
    __shared__ __align__(16) short As[64 * 200];
    __shared__ __align__(16) short Bs[64 * 200];
    int tid = threadIdx.x;
    int m0 = blockIdx.x * 64;
    int n0 = blockIdx.y * 64;
    for (int e = tid; e < 64 * 24; e += 256) {
        int m = e / 24, kc = (e % 24) * 8;
        uint4 raw = *(const uint4*)(Abuf + (size_t)(m0 + m) * C + kc);
        if (HASGAIN) {
            unsigned short* u = (unsigned short*)&raw;
            unsigned short o[8];
            #pragma unroll
            for (int j = 0; j < 8; ++j) o[j] = f2bits(bits2f(u[j]) * gain[kc + j] + beta[kc + j]);
            *(uint4*)&As[m * 200 + kc] = *(uint4*)o;
        } else {
            *(uint4*)&As[m * 200 + kc] = raw;
        }
    }
    for (int e = tid; e < 64 * 24; e += 256) {
        int n = e / 24, kc = (e % 24) * 8;
        *(uint4*)&Bs[n * 200 + kc] = *(const uint4*)(Wt + (size_t)(n0 + n) * C + kc);
    }
    __syncthreads();
    int w = tid >> 6, lane = tid & 63;
    int wm = (w >> 1) * 32, wn = (w & 1) * 32;
    int lr = lane & 15, lk = (lane >> 4) * 8;
    f32x4 acc00 = {0.f,0.f,0.f,0.f}, acc01 = acc00, acc10 = acc00, acc11 = acc00;
    #pragma unroll
    for (int ks = 0; ks < 6; ++ks) {
        int k0 = ks * 32 + lk;
        bf16x8 a0 = *(bf16x8*)&As[(wm + lr) * 200 + k0];
        bf16x8 a1 = *(bf16x8*)&As[(wm + 16 + lr) * 200 + k0];
        bf16x8 b0 = *(bf16x8*)&Bs[(wn + lr) * 200 + k0];
        bf16x8 b1 = *(bf16x8*)&Bs[(wn + 16 + lr) * 200 + k0];
        acc00 = __builtin_amdgcn_mfma_f32_16x16x32_bf16(a0, b0, acc00, 0, 0, 0);
        acc01 = __builtin_amdgcn_mfma_f32_16x16x32_bf16(a0, b1, acc01, 0, 0, 0);
        acc10 = __builtin_amdgcn_mfma_f32_16x16x32_bf16(a1, b0, acc10, 0, 0, 0);
        acc11 = __builtin_amdgcn_mfma_f32_16x16x32_bf16(a1, b1, acc11, 0, 0, 0);
    }
    int rbase = (lane >> 4) * 4;
    f32x4 accs[2][2] = {{acc00, acc01}, {acc10, acc11}};
    #pragma unroll
    for (int mt = 0; mt < 2; ++mt) {
        #pragma unroll
        for (int nt = 0; nt < 2; ++nt) {
            int co = n0 + wn + nt * 16 + lr;
            float bv = bias[co];
            #pragma unroll
            for (int r = 0; r < 4; ++r) {
                int tok = m0 + wm + mt * 16 + rbase + r;
                float v = accs[mt][nt][r] + bv;
                if (MODE == 0) outb[(size_t)tok * OUTLD + co] = f2b(v);
                else if (MODE == 1) outb[(size_t)tok * OUTLD + co] = f2b(gelu_exact(v));
                else outf[(size_t)tok * OUTLD + co] += v;
            }
        }
    }
}

// ---------- Stable counting sort by tk_id ----------
__global__ void k_sort_count(const int* tk_id, int* chunk_cnt) {
    int c = blockIdx.x, b = blockIdx.y;
    int tid = threadIdx.x;               // 128
    __shared__ int cnt[M];
    cnt[tid] = 0;
    __syncthreads();
    atomicAdd(&cnt[tk_id[b * N + c * 128 + tid]], 1);
    __syncthreads();
    chunk_cnt[(b * 128 + c) * M + tid] = cnt[tid];
}

__global__ void k_sort_scan(int* chunk_cnt) {
    int b = blockIdx.x;
    int k = threadIdx.x;
    int tot = 0;
    for (int c = 0; c < 128; ++c) tot += chunk_cnt[(b * 128 + c) * M + k];
    __shared__ int totals[M];
    __shared__ int base[M];
    totals[k] = tot;
    __syncthreads();
    if (k == 0) {
        int run = 0;
        for (int kk = 0; kk < M; ++kk) { base[kk] = run; run += totals[kk]; }
    }
    __syncthreads();
    int run = base[k];
    for (int c = 0; c < 128; ++c) {
        int v = chunk_cnt[(b * 128 + c) * M + k];
        chunk_cnt[(b * 128 + c) * M + k] = run;
        run += v;
    }
}

__global__ void k_sort_scatter(const int* tk_id, const int* chunk_cnt, int* sort_idx) {
    int c = blockIdx.x, b = blockIdx.y;
    int k = threadIdx.x;
    __shared__ int keys[128];
    keys[k] = tk_id[b * N + c * 128 + k];
    __syncthreads();
    int off = chunk_cnt[(b * 128 + c) * M + k];
    for (int j = 0; j < 128; ++j) {
        if (keys[j] == k) sort_idx[b * N + off++] = c * 128 + j;
    }
}

// ---------- MFMA grouped self-attention: block = (group, head, batch) ----------
__global__ void __launch_bounds__(256) k_attn_mfma(const bf16* qkv, const int* sort_idx, bf16* o_buf) {
    int g = blockIdx.x, h = blockIdx.y, b = blockIdx.z;
    __shared__ int sidx[GS];
    __shared__ __align__(16) unsigned short Kl[256 * 64];   // [key][64d], 16B-blk ^ (key&7)
    __shared__ __align__(16) unsigned short Vt[48 * 256];   // [d][256key], 16B-blk ^ (d&7)
    __shared__ __align__(16) unsigned short Pl[4][64 * 32]; // per-wave [64q][32key], 16B-blk ^ (q&3)
    int tid = threadIdx.x;
    sidx[tid] = sort_idx[b * N + g * GS + tid];
    __syncthreads();
    {
        int row = tid;
        int srow = sidx[row];
        size_t kb = ((size_t)(b * N + srow)) * TC3 + C + h * HD;
        size_t vb = ((size_t)(b * N + srow)) * TC3 + 2 * C + h * HD;
        #pragma unroll
        for (int db = 0; db < 6; ++db) {
            uint4 kv = *(const uint4*)(qkv + kb + db * 8);
            *(uint4*)&Kl[row * 64 + ((db ^ (row & 7)) * 8)] = kv;
            uint4 vv4 = *(const uint4*)(qkv + vb + db * 8);
            unsigned short* vu = (unsigned short*)&vv4;
            #pragma unroll
            for (int j = 0; j < 8; ++j) {
                int d = db * 8 + j;
                Vt[d * 256 + (((row >> 3) ^ (d & 7)) * 8) + (row & 7)] = vu[j];
            }
        }
        uint4 z = {0u,0u,0u,0u};
        *(uint4*)&Kl[row * 64 + ((6 ^ (row & 7)) * 8)] = z;
        *(uint4*)&Kl[row * 64 + ((7 ^ (row & 7)) * 8)] = z;
    }
    __syncthreads();
    int w = tid >> 6, l = tid & 63;
    int lq = l & 15, g8 = l >> 4;
    // Q fragments (held in regs for the whole kernel)
    bf16x8 qf[4][2];
    #pragma unroll
    for (int qt = 0; qt < 4; ++qt) {
        int qrow = sidx[w * 64 + qt * 16 + lq];
        size_t qb = ((size_t)(b * N + qrow)) * TC3 + h * HD;
        qf[qt][0] = *(const bf16x8*)(qkv + qb + g8 * 8);
        int d1 = 32 + g8 * 8;
        if (d1 < HD) qf[qt][1] = *(const bf16x8*)(qkv + qb + d1);
        else { uint4 z = {0u,0u,0u,0u}; qf[qt][1] = *(bf16x8*)&z; }
    }
    float mrun[4], lrun[4];
    f32x4 Oa[4][3];
    #pragma unroll
    for (int qt = 0; qt < 4; ++qt) {
        mrun[qt] = -1e30f; lrun[qt] = 0.f;
        #pragma unroll
        for (int dt = 0; dt < 3; ++dt) Oa[qt][dt] = (f32x4){0.f,0.f,0.f,0.f};
    }
    unsigned short* Pw = &Pl[w][0];
    for (int ck = 0; ck < 8; ++ck) {
        int kbase = ck * 32;
        bf16x8 kf[2][2];
        #pragma unroll
        for (int kt = 0; kt < 2; ++kt) {
            int key = kbase + kt * 16 + lq;
            #pragma unroll
            for (int ks = 0; ks < 2; ++ks)
                kf[kt][ks] = *(bf16x8*)&Kl[key * 64 + (((ks * 4 + g8) ^ (key & 7)) * 8)];
        }
        bf16x8 vf[3];
        #pragma unroll
        for (int dt = 0; dt < 3; ++dt) {
            int d = dt * 16 + lq;
            vf[dt] = *(bf16x8*)&Vt[d * 256 + ((((kbase >> 3) + g8) ^ (d & 7)) * 8)];
        }
        #pragma unroll
        for (int qt = 0; qt < 4; ++qt) {
            f32x4 s0 = {0.f,0.f,0.f,0.f}, s1 = s0;
            s0 = __builtin_amdgcn_mfma_f32_16x16x32_bf16(kf[0][0], qf[qt][0], s0, 0, 0, 0);
            s0 = __builtin_amdgcn_mfma_f32_16x16x32_bf16(kf[0][1], qf[qt][1], s0, 0, 0, 0);
            s1 = __builtin_amdgcn_mfma_f32_16x16x32_bf16(kf[1][0], qf[qt][0], s1, 0, 0, 0);
            s1 = __builtin_amdgcn_mfma_f32_16x16x32_bf16(kf[1][1], qf[qt][1], s1, 0, 0, 0);
            // scaled scores; softmax over chunk (keys spread over r and g8-groups)
            float sv0[4], sv1[4];
            float cmax = -1e30f;
            #pragma unroll
            for (int r = 0; r < 4; ++r) {
                sv0[r] = s0[r] * ATT_SCALE; sv1[r] = s1[r] * ATT_SCALE;
                cmax = fmaxf(cmax, fmaxf(sv0[r], sv1[r]));
            }
            cmax = fmaxf(cmax, __shfl_xor(cmax, 16));
            cmax = fmaxf(cmax, __shfl_xor(cmax, 32));
            float mnew = fmaxf(mrun[qt], cmax);
            float sf = expf(mrun[qt] - mnew);
            float p0[4], p1[4], csum = 0.f;
            #pragma unroll
            for (int r = 0; r < 4; ++r) {
                p0[r] = expf(sv0[r] - mnew); p1[r] = expf(sv1[r] - mnew);
                csum += p0[r] + p1[r];
            }
            csum += __shfl_xor(csum, 16);
            csum += __shfl_xor(csum, 32);
            lrun[qt] = lrun[qt] * sf + csum;
            mrun[qt] = mnew;
            // write P (bf16) to per-wave LDS: rows q, keys of this chunk
            int q = qt * 16 + lq;
            {
                unsigned short pw[4];
                #pragma unroll
                for (int r = 0; r < 4; ++r) pw[r] = f2bits(p0[r]);
                int slot = g8;                       // keys 4*slot..+3  (kt=0)
                int addr = q * 32 + (((slot >> 1) ^ (q & 3)) * 8) + (slot & 1) * 4;
                *(uint2*)&Pw[addr] = *(uint2*)pw;
                #pragma unroll
                for (int r = 0; r < 4; ++r) pw[r] = f2bits(p1[r]);
                slot = 4 + g8;                       // kt=1
                addr = q * 32 + (((slot >> 1) ^ (q & 3)) * 8) + (slot & 1) * 4;
                *(uint2*)&Pw[addr] = *(uint2*)pw;
            }
            // rescale O rows (rows are q = qt*16 + 4*g8 + r, sf indexed by lq)
            float sfr[4];
            #pragma unroll
            for (int r = 0; r < 4; ++r) sfr[r] = __shfl(sf, 4 * g8 + r);
            #pragma unroll
            for (int dt = 0; dt < 3; ++dt)
                #pragma unroll
                for (int r = 0; r < 4; ++r) Oa[qt][dt][r] *= sfr[r];
            // PV: a-frag = P[q][8 keys], b-frag = vf
            bf16x8 pa = *(bf16x8*)&Pw[q * 32 + ((g8 ^ (lq & 3)) * 8)];
            #pragma unroll
            for (int dt = 0; dt < 3; ++dt)
                Oa[qt][dt] = __builtin_amdgcn_mfma_f32_16x16x32_bf16(pa, vf[dt], Oa[qt][dt], 0, 0, 0);
        }
    }
    // epilogue: divide by lsum, scatter-store (unsort)
    #pragma unroll
    for (int qt = 0; qt < 4; ++qt) {
        float invq = 1.0f / lrun[qt];
        float invr[4];
        #pragma unroll
        for (int r = 0; r < 4; ++r) invr[r] = __shfl(invq, 4 * g8 + r);
        #pragma unroll
        for (int r = 0; r < 4; ++r) {
            int grow = sidx[w * 64 + qt * 16 + 4 * g8 + r];
            size_t obase = ((size_t)(b * N + grow)) * C + h * HD;
            #pragma unroll
            for (int dt = 0; dt < 3; ++dt)
                o_buf[obase + dt * 16 + lq] = f2b(Oa[qt][dt][r] * invr[r]);
        }
    }
}

// ---------- td feature gather into hcat tail columns ----------
__global__ void k_tdfill(const int* tk_id, const float* tdf, bf16* hcat) {
    int idx = blockIdx.x * 256 + threadIdx.x;
    if (idx >= B * N * TDF) return;
    int tok = idx >> 4, f = idx & 15;
    hcat[(size_t)tok * HIDT + HID + f] = f2b(tdf[tk_id[tok] * TDF + f]);
}

// ---------- depthwise 5x5 conv, tiled: 16x16 spatial x 16 ch ----------
__global__ void __launch_bounds__(256) k_conv(const bf16* hcat, const float* dw_w, const float* dw_b,
                                              bf16* convsum) {
    int st = blockIdx.x;
    int c16 = blockIdx.y;
    int b = blockIdx.z;
    int ty = (st >> 3) * 16, tx = (st & 7) * 16;
    int tid = threadIdx.x;
    __shared__ __align__(16) unsigned short Hs[400 * 16];
    __shared__ float Ws[16 * 25];
    __shared__ float Wb[16];
    for (int e = tid; e < 400; e += 256) {
        int ch = e / 25, tap = e % 25;
        Ws[e] = dw_w[(size_t)(c16 * 16 + ch) * 25 + tap];
    }
    if (tid < 16) Wb[tid] = dw_b[c16 * 16 + tid];
    for (int e = tid; e < 800; e += 256) {
        int pos = e >> 1, cc = e & 1;
        int py = pos / 20, px = pos % 20;
        int gy = ty + py - 2, gx = tx + px - 2;
        uint4 v = {0u, 0u, 0u, 0u};
        if (gy >= 0 && gy < Hh && gx >= 0 && gx < Ww)
            v = *(const uint4*)(hcat + ((size_t)b * N + gy * Ww + gx) * HIDT + c16 * 16 + cc * 8);
        *(uint4*)&Hs[pos * 16 + cc * 8] = v;
    }
    __syncthreads();
    #pragma unroll
    for (int j = 0; j < 2; ++j) {
        int item = tid + 256 * j;
        int pos = item >> 1, cc = item & 1;
        int ly = pos >> 4, lx = pos & 15;
        float a8[8];
        #pragma unroll
        for (int ch = 0; ch < 8; ++ch) a8[ch] = 0.f;
        #pragma unroll
        for (int ky = 0; ky < 5; ++ky) {
            #pragma unroll
            for (int kx = 0; kx < 5; ++kx) {
                uint4 hv = *(uint4*)&Hs[((ly + ky) * 20 + lx + kx) * 16 + cc * 8];
                unsigned short* hu = (unsigned short*)&hv;
                #pragma unroll
                for (int ch = 0; ch < 8; ++ch)
                    a8[ch] += bits2f(hu[ch]) * Ws[(cc * 8 + ch) * 25 + ky * 5 + kx];
            }
        }
        uint4 cv4 = *(uint4*)&Hs[((ly + 2) * 20 + lx + 2) * 16 + cc * 8];
        unsigned short* cu = (unsigned short*)&cv4;
        unsigned short ow[8];
        #pragma unroll
        for (int ch = 0; ch < 8; ++ch)
            ow[ch] = f2bits(bits2f(cu[ch]) + gelu_exact(a8[ch] + Wb[cc * 8 + ch]));
        int gy = ty + ly, gx = tx + lx;
        *(uint4*)(convsum + ((size_t)b * N + gy * Ww + gx) * HIDT + c16 * 16 + cc * 8) = *(uint4*)ow;
    }
}

// ---------- fc2 (K=784) MFMA + bias + LN3 + residual + transposed store ----------
__global__ void __launch_bounds__(256) k_fc2ln(const bf16* convsum, const bf16* Wt,  // Wt [192][784]
                                               const float* bias, const float* g3, const float* b3,
                                               const float* accres, float* out) {
    __shared__ __align__(16) unsigned short As[64 * 64];
    __shared__ __align__(16) unsigned short Bs[192 * 64];
    int tid = threadIdx.x;
    int m0 = blockIdx.x * 64;
    int w = tid >> 6, lane = tid & 63;
    int lr = lane & 15, g8 = lane >> 4;
    f32x4 acc[12];
    #pragma unroll
    for (int nt = 0; nt < 12; ++nt) acc[nt] = (f32x4){0.f, 0.f, 0.f, 0.f};
    for (int kc = 0; kc < 13; ++kc) {
        int kb = kc * 64;
        for (int e = tid; e < 512; e += 256) {
            int m = e >> 3, k8 = (e & 7) * 8;
            uint4 v = {0u,0u,0u,0u};
            if (kb + k8 < HIDT) v = *(const uint4*)(convsum + (size_t)(m0 + m) * HIDT + kb + k8);
            *(uint4*)&As[m * 64 + (((e & 7) ^ (m & 7)) * 8)] = v;
        }
        for (int e = tid; e < 1536; e += 256) {
            int n = e >> 3, k8 = (e & 7) * 8;
            uint4 v = {0u,0u,0u,0u};
            if (kb + k8 < HIDT) v = *(const uint4*)(Wt + (size_t)n * HIDT + kb + k8);
            *(uint4*)&Bs[n * 64 + (((e & 7) ^ (n & 7)) * 8)] = v;
        }
        __syncthreads();
        #pragma unroll
        for (int ks = 0; ks < 2; ++ks) {
            int kg = ks * 4 + g8;
            int arow = w * 16 + lr;
            bf16x8 a = *(bf16x8*)&As[arow * 64 + ((kg ^ (arow & 7)) * 8)];
            #pragma unroll
            for (int nt = 0; nt < 12; ++nt) {
                int nrow = nt * 16 + lr;
                bf16x8 bfr = *(bf16x8*)&Bs[nrow * 64 + ((kg ^ (nrow & 7)) * 8)];
                acc[nt] = __builtin_amdgcn_mfma_f32_16x16x32_bf16(a, bfr, acc[nt], 0, 0, 0);
            }
        }
        __syncthreads();
    }
    #pragma unroll
    for (int nt = 0; nt < 12; ++nt) {
        float bv = bias[nt * 16 + lr];
        #pragma unroll
        for (int r = 0; r < 4; ++r) acc[nt][r] += bv;
    }
    #pragma unroll
    for (int r = 0; r < 4; ++r) {
        float s = 0.f, ss = 0.f;
        #pragma unroll
        for (int nt = 0; nt < 12; ++nt) { float v = acc[nt][r]; s += v; ss += v * v; }
        s += __shfl_xor(s, 1); ss += __shfl_xor(ss, 1);
        s += __shfl_xor(s, 2); ss += __shfl_xor(ss, 2);
        s += __shfl_xor(s, 4); ss += __shfl_xor(ss, 4);
        s += __shfl_xor(s, 8); ss += __shfl_xor(ss, 8);
        float mu = s / C;
        float rstd = rsqrtf(ss / C - mu * mu + 1e-5f);
        int tok = m0 + w * 16 + g8 * 4 + r;
        int b = tok / N, i = tok % N;
        #pragma unroll
        for (int nt = 0; nt < 12; ++nt) {
            int c = nt * 16 + lr;
            float o = accres[(size_t)tok * C + c] + (acc[nt][r] - mu) * rstd * g3[c] + b3[c];
            out[((size_t)b * C + c) * N + i] = o;
        }
    }
}

__global__ void k_sentinel(float* out, int nelem) {
    int i = blockIdx.x * blockDim.x + threadIdx.x;
    if (i < nelem) out[i] = 1234.0f;
}

extern "C" void kernel_launch(void* const* d_in, const int* in_sizes, int n_in,
                              void* d_out, int out_size, void* d_ws, size_t ws_size,
                              hipStream_t stream) {
    const float* x        = (const float*)d_in[0];
    const float* td       = (const float*)d_in[2];
    const float* g1       = (const float*)d_in[3];
    const float* b1       = (const float*)d_in[4];
    const float* g2       = (const float*)d_in[5];
    const float* b2v      = (const float*)d_in[6];
    const float* g3       = (const float*)d_in[7];
    const float* b3       = (const float*)d_in[8];
    const float* wq_w     = (const float*)d_in[9];
    const float* wq_b     = (const float*)d_in[10];
    const float* wk_w     = (const float*)d_in[11];
    const float* wk_b     = (const float*)d_in[12];
    const float* wv_w     = (const float*)d_in[13];
    const float* wv_b     = (const float*)d_in[14];
    const float* ca_scale = (const float*)d_in[15];
    const float* wqkv_w   = (const float*)d_in[16];
    const float* wqkv_b   = (const float*)d_in[17];
    const float* proj_w   = (const float*)d_in[18];
    const float* proj_b   = (const float*)d_in[19];
    const float* fc_td_w  = (const float*)d_in[20];
    const float* fc_td_b  = (const float*)d_in[21];
    const float* fc1_w    = (const float*)d_in[22];
    const float* fc1_b    = (const float*)d_in[23];
    const float* dw_w     = (const float*)d_in[24];
    const float* dw_b     = (const float*)d_in[25];
    const float* fc2_w    = (const float*)d_in[26];
    const float* fc2_b    = (const float*)d_in[27];
    float* out = (float*)d_out;

    char* ws = (char*)d_ws;
    size_t off = 0;
    auto alloc = [&](size_t bytes) { size_t o = off; off += (bytes + 255) & ~(size_t)255; return o; };
    size_t o_t     = alloc((size_t)B * N * C * 2);
    size_t o_xn32  = alloc((size_t)B * N * C * 4);
    size_t o_acc   = alloc((size_t)B * N * C * 4);
    size_t o_qkv   = alloc((size_t)B * N * TC3 * 2);
    size_t o_obuf  = alloc((size_t)B * N * C * 2);
    size_t o_hcat  = alloc((size_t)B * N * HIDT * 2);
    size_t o_conv  = alloc((size_t)B * N * HIDT * 2);
    size_t o_kn    = alloc((size_t)M * RD * 4);
    size_t o_vv    = alloc((size_t)M * C * 4);
    size_t o_tdf   = alloc((size_t)M * TDF * 4);
    size_t o_tk    = alloc((size_t)B * N * 4);
    size_t o_sidx  = alloc((size_t)B * N * 4);
    size_t o_ccnt  = alloc((size_t)B * 128 * M * 4);
    size_t o_wqkvT = alloc((size_t)TC3 * C * 2);
    size_t o_projT = alloc((size_t)C * C * 2);
    size_t o_fc1T  = alloc((size_t)HID * C * 2);
    size_t o_fc2T  = alloc((size_t)C * HIDT * 2);

    if (ws_size < off) {
        k_sentinel<<<(out_size + 255) / 256, 256, 0, stream>>>(out, out_size);
        return;
    }

    bf16*  t_buf   = (bf16*)(ws + o_t);
    float* xn32    = (float*)(ws + o_xn32);
    float* acc     = (float*)(ws + o_acc);
    bf16*  qkv     = (bf16*)(ws + o_qkv);
    bf16*  o_bufp  = (bf16*)(ws + o_obuf);
    bf16*  hcat    = (bf16*)(ws + o_hcat);
    bf16*  convsum = (bf16*)(ws + o_conv);
    float* kn      = (float*)(ws + o_kn);
    float* vv      = (float*)(ws + o_vv);
    float* tdf     = (float*)(ws + o_tdf);
    int*   tk_id   = (int*)(ws + o_tk);
    int*   sidx    = (int*)(ws + o_sidx);
    int*   ccnt    = (int*)(ws + o_ccnt);
    bf16*  wqkvT   = (bf16*)(ws + o_wqkvT);
    bf16*  projT   = (bf16*)(ws + o_projT);
    bf16*  fc1T    = (bf16*)(ws + o_fc1T);
    bf16*  fc2T    = (bf16*)(ws + o_fc2T);

    // weight pre-transpose+convert (once per launch, small)
    k_wtrans<<<dim3(TC3 / 64, C / 64), 256, 0, stream>>>(wqkv_w, wqkvT, C, TC3);
    k_wtrans<<<dim3(C / 64, C / 64), 256, 0, stream>>>(proj_w, projT, C, C);
    k_wtrans<<<dim3(HID / 64, C / 64), 256, 0, stream>>>(fc1_w, fc1T, C, HID);
    k_wtrans<<<dim3(C / 64, (HIDT + 63) / 64), 256, 0, stream>>>(fc2_w, fc2T, HIDT, C);

    k_precompute<<<M, 64, 0, stream>>>(td, wk_w, wk_b, wv_w, wv_b, fc_td_w, fc_td_b, kn, vv, tdf);
    k_ln<<<B * N / 64, 256, 0, stream>>>(x, t_buf, xn32, acc);
    k_atdca<<<B * N / 4, 256, 0, stream>>>(xn32, g1, b1, wq_w, wq_b, ca_scale, kn, vv, acc, tk_id);
    k_gemm192<TC3, TC3, 0, true><<<dim3(B * N / 64, TC3 / 64), 256, 0, stream>>>(
        t_buf, g1, b1, wqkvT, wqkv_b, qkv, nullptr);
    k_sort_count<<<dim3(128, B), 128, 0, stream>>>(tk_id, ccnt);
    k_sort_scan<<<B, 128, 0, stream>>>(ccnt);
    k_sort_scatter<<<dim3(128, B), 128, 0, stream>>>(tk_id, ccnt, sidx);
    k_attn_mfma<<<dim3(NG, HEADS, B), 256, 0, stream>>>(qkv, sidx, o_bufp);
    k_gemm192<C, C, 2, false><<<dim3(B * N / 64, C / 64), 256, 0, stream>>>(
        o_bufp, nullptr, nullptr, projT, proj_b, nullptr, acc);
    k_gemm192<HID, HIDT, 1, true><<<dim3(B * N / 64, HID / 64), 256, 0, stream>>>(
        t_buf, g2, b2v, fc1T, fc1_b, hcat, nullptr);
    k_tdfill<<<(B * N * TDF + 255) / 256, 256, 0, stream>>>(tk_id, tdf, hcat);
    k_conv<<<dim3(64, 49, B), 256, 0, stream>>>(hcat, dw_w, dw_b, convsum);
    k_fc2ln<<<B * N / 64, 256, 0, stream>>>(convsum, fc2T, fc2_b, g3, b3, acc, out);
}

// Round 6
// 595.217 us; speedup vs baseline: 5.0393x; 1.0676x over previous
//
#include <hip/hip_runtime.h>
#include <hip/hip_bf16.h>
#include <math.h>

using bf16 = __hip_bfloat16;

static constexpr int B = 2, C = 192, Hh = 128, Ww = 128, N = Hh * Ww;
static constexpr int M = 128, RD = 10, GS = 256, NG = N / GS;
static constexpr int HEADS = 4, HD = C / HEADS;                      // 48
static constexpr int TDF = 16, HID = 4 * C, HIDT = HID + TDF;        // 768, 784
static constexpr int TC3 = 3 * C;                                    // 576
static constexpr float LOG_M = 4.852030263919617f;                   // ln(128)
static constexpr float ATT_SCALE = 0.14433756729740643f;             // 48^-0.5

typedef __attribute__((ext_vector_type(8))) short bf16x8;
typedef __attribute__((ext_vector_type(4))) float f32x4;

__device__ __forceinline__ float b2f(bf16 v) { return __bfloat162float(v); }
__device__ __forceinline__ bf16 f2b(float v) { return __float2bfloat16(v); }
__device__ __forceinline__ float bits2f(unsigned short u) { return __uint_as_float(((unsigned)u) << 16); }
__device__ __forceinline__ unsigned short f2bits(float f) {
    union { bf16 h; unsigned short u; } cv; cv.h = f2b(f); return cv.u;
}
__device__ __forceinline__ float gelu_exact(float v) {
    return 0.5f * v * (1.0f + erff(v * 0.70710678118654752f));
}

// ---------- weight transpose+convert: in[K][Nn] f32 -> out[Nn][K] bf16 ----------
__global__ void __launch_bounds__(256) k_wtrans(const float* in, bf16* out, int K, int Nn) {
    __shared__ float T[64][65];
    int n0 = blockIdx.x * 64, k0 = blockIdx.y * 64;
    int tid = threadIdx.x;
    for (int e = tid; e < 4096; e += 256) {
        int kk = e >> 6, nn = e & 63;
        if (k0 + kk < K) T[kk][nn] = in[(size_t)(k0 + kk) * Nn + n0 + nn];
    }
    __syncthreads();
    for (int e = tid; e < 4096; e += 256) {
        int nn = e >> 6, kk = e & 63;
        if (k0 + kk < K) out[(size_t)(n0 + nn) * K + k0 + kk] = f2b(T[kk][nn]);
    }
}

// ---------- K0: token-dict precompute: kn, v, td_feat ----------
__global__ void k_precompute(const float* td, const float* wk_w, const float* wk_b,
                             const float* wv_w, const float* wv_b,
                             const float* fc_td_w, const float* fc_td_b,
                             float* kn, float* vv, float* tdf) {
    int m = blockIdx.x;
    int lane = threadIdx.x;      // 64
    __shared__ float trow[C];
    for (int ch = lane; ch < C; ch += 64) trow[ch] = td[m * C + ch];
    __syncthreads();
    __shared__ float ks[RD];
    __shared__ float inv_s;
    if (lane < RD) {
        float s = wk_b[lane];
        for (int ch = 0; ch < C; ++ch) s += trow[ch] * wk_w[ch * RD + lane];
        ks[lane] = s;
    }
    __syncthreads();
    if (lane == 0) {
        float ss = 0.f;
        for (int r = 0; r < RD; ++r) ss += ks[r] * ks[r];
        inv_s = 1.0f / fmaxf(sqrtf(ss), 1e-12f);
    }
    __syncthreads();
    if (lane < RD) kn[m * RD + lane] = ks[lane] * inv_s;
    for (int c0 = 0; c0 < 3; ++c0) {
        int co = lane + 64 * c0;
        float s = wv_b[co];
        for (int ch = 0; ch < C; ++ch) s += trow[ch] * wv_w[ch * C + co];
        vv[m * C + co] = s;
    }
    if (lane < TDF) {
        float s = fc_td_b[lane];
        for (int ch = 0; ch < C; ++ch) s += trow[ch] * fc_td_w[ch * TDF + lane];
        tdf[m * TDF + lane] = s;
    }
}

// ---------- K1: LN core via LDS transpose: t(bf16), xn32(fp32), acc=x ----------
__global__ void __launch_bounds__(256) k_ln(const float* x, bf16* t, float* xn32, float* acc) {
    __shared__ float Xs[64 * 193];
    __shared__ float mu_s[64], rs_s[64];
    int tid = threadIdx.x;
    int m0 = blockIdx.x * 64;
    int b = m0 / N, i0 = m0 % N;
    for (int e = tid; e < 192 * 64; e += 256) {
        int ch = e >> 6, ii = e & 63;
        Xs[ii * 193 + ch] = x[((size_t)b * C + ch) * N + i0 + ii];
    }
    __syncthreads();
    {
        int tok = tid >> 2, part = tid & 3;
        float s = 0.f, ss = 0.f;
        for (int ch = part * 48; ch < part * 48 + 48; ++ch) {
            float v = Xs[tok * 193 + ch]; s += v; ss += v * v;
        }
        s += __shfl_xor(s, 1); ss += __shfl_xor(ss, 1);
        s += __shfl_xor(s, 2); ss += __shfl_xor(ss, 2);
        if (part == 0) {
            float mu = s / C;
            mu_s[tok] = mu;
            rs_s[tok] = rsqrtf(ss / C - mu * mu + 1e-5f);
        }
    }
    __syncthreads();
    for (int e = tid; e < 64 * 192; e += 256) {
        int ii = e / 192, ch = e % 192;
        float v = Xs[ii * 193 + ch];
        float xn = (v - mu_s[ii]) * rs_s[ii];
        size_t g = (size_t)(m0 + ii);
        t[g * C + ch] = f2b(xn);
        xn32[g * C + ch] = xn;
        acc[g * C + ch] = v;
    }
}

// ---------- K2: ATD_CA ----------
__global__ void __launch_bounds__(256) k_atdca(const float* xn32, const float* g1, const float* b1,
                        const float* wq_w, const float* wq_b, const float* ca_scale,
                        const float* kn, const float* vv,
                        float* acc, int* tk_id) {
    int t0 = blockIdx.x * 4;
    int w = threadIdx.x >> 6, lane = threadIdx.x & 63;
    int g = t0 + w;
    __shared__ float p_s[4][M];
    float xn[3];
    #pragma unroll
    for (int k = 0; k < 3; ++k) {
        int ch = lane + 64 * k;
        xn[k] = xn32[(size_t)g * C + ch] * g1[ch] + b1[ch];
    }
    float q[RD];
    #pragma unroll
    for (int r = 0; r < RD; ++r) {
        float p = 0.f;
        #pragma unroll
        for (int k = 0; k < 3; ++k) { int ch = lane + 64 * k; p += xn[k] * wq_w[ch * RD + r]; }
        for (int mk = 32; mk >= 1; mk >>= 1) p += __shfl_xor(p, mk);
        q[r] = p + wq_b[r];
    }
    float ssn = 0.f;
    #pragma unroll
    for (int r = 0; r < RD; ++r) ssn += q[r] * q[r];
    float invq = 1.0f / fmaxf(sqrtf(ssn), 1e-12f);
    float s0 = 0.f, s1 = 0.f;
    #pragma unroll
    for (int r = 0; r < RD; ++r) {
        float qr = q[r] * invq;
        s0 += qr * kn[lane * RD + r];
        s1 += qr * kn[(lane + 64) * RD + r];
    }
    float mv; int mi;
    if (s1 > s0) { mv = s1; mi = lane + 64; } else { mv = s0; mi = lane; }
    for (int mk = 32; mk >= 1; mk >>= 1) {
        float ov = __shfl_xor(mv, mk); int oi = __shfl_xor(mi, mk);
        if (ov > mv || (ov == mv && oi < mi)) { mv = ov; mi = oi; }
    }
    float cs = ca_scale[0]; cs = fminf(fmaxf(cs, 0.0f), 3.0f);
    float scale = 1.0f + cs * LOG_M;
    float e0 = expf((s0 - mv) * scale), e1 = expf((s1 - mv) * scale);
    float sum = e0 + e1;
    for (int mk = 32; mk >= 1; mk >>= 1) sum += __shfl_xor(sum, mk);
    float invs = 1.0f / sum;
    p_s[w][lane] = e0 * invs;
    p_s[w][lane + 64] = e1 * invs;
    if (lane == 0) tk_id[g] = mi;
    __syncthreads();
    for (int e = threadIdx.x; e < 4 * C; e += 256) {
        int tok = e / C, ch = e % C;
        float a = 0.f;
        const float* vp = vv + ch;
        #pragma unroll 4
        for (int m = 0; m < M; ++m) a += p_s[tok][m] * vp[m * C];
        acc[(size_t)(t0 + tok) * C + ch] += a;
    }
}

// ---------- MFMA GEMM, K=192, Wt = transposed bf16 [NOUT][192] ----------
template<int NOUT, int OUTLD, int MODE, bool HASGAIN>
__global__ void __launch_bounds__(256) k_gemm192(const bf16* Abuf, const float* gain, const float* beta,
                                                 const bf16* Wt, const float* bias,
                                                 bf16* outb, float* outf) {
    __shared__ __align__(16) short As[64 * 200];
    __shared__ __align__(16) short Bs[64 * 200];
    int tid = threadIdx.x;
    int m0 = blockIdx.x * 64;
    int n0 = blockIdx.y * 64;
    for (int e = tid; e < 64 * 24; e += 256) {
        int m = e / 24, kc = (e % 24) * 8;
        uint4 raw = *(const uint4*)(Abuf + (size_t)(m0 + m) * C + kc);
        if (HASGAIN) {
            unsigned short* u = (unsigned short*)&raw;
            unsigned short o[8];
            #pragma unroll
            for (int j = 0; j < 8; ++j) o[j] = f2bits(bits2f(u[j]) * gain[kc + j] + beta[kc + j]);
            *(uint4*)&As[m * 200 + kc] = *(uint4*)o;
        } else {
            *(uint4*)&As[m * 200 + kc] = raw;
        }
    }
    for (int e = tid; e < 64 * 24; e += 256) {
        int n = e / 24, kc = (e % 24) * 8;
        *(uint4*)&Bs[n * 200 + kc] = *(const uint4*)(Wt + (size_t)(n0 + n) * C + kc);
    }
    __syncthreads();
    int w = tid >> 6, lane = tid & 63;
    int wm = (w >> 1) * 32, wn = (w & 1) * 32;
    int lr = lane & 15, lk = (lane >> 4) * 8;
    f32x4 acc00 = {0.f,0.f,0.f,0.f}, acc01 = acc00, acc10 = acc00, acc11 = acc00;
    #pragma unroll
    for (int ks = 0; ks < 6; ++ks) {
        int k0 = ks * 32 + lk;
        bf16x8 a0 = *(bf16x8*)&As[(wm + lr) * 200 + k0];
        bf16x8 a1 = *(bf16x8*)&As[(wm + 16 + lr) * 200 + k0];
        bf16x8 b0 = *(bf16x8*)&Bs[(wn + lr) * 200 + k0];
        bf16x8 b1 = *(bf16x8*)&Bs[(wn + 16 + lr) * 200 + k0];
        acc00 = __builtin_amdgcn_mfma_f32_16x16x32_bf16(a0, b0, acc00, 0, 0, 0);
        acc01 = __builtin_amdgcn_mfma_f32_16x16x32_bf16(a0, b1, acc01, 0, 0, 0);
        acc10 = __builtin_amdgcn_mfma_f32_16x16x32_bf16(a1, b0, acc10, 0, 0, 0);
        acc11 = __builtin_amdgcn_mfma_f32_16x16x32_bf16(a1, b1, acc11, 0, 0, 0);
    }
    int rbase = (lane >> 4) * 4;
    f32x4 accs[2][2] = {{acc00, acc01}, {acc10, acc11}};
    #pragma unroll
    for (int mt = 0; mt < 2; ++mt) {
        #pragma unroll
        for (int nt = 0; nt < 2; ++nt) {
            int co = n0 + wn + nt * 16 + lr;
            float bv = bias[co];
            #pragma unroll
            for (int r = 0; r < 4; ++r) {
                int tok = m0 + wm + mt * 16 + rbase + r;
                float v = accs[mt][nt][r] + bv;
                if (MODE == 0) outb[(size_t)tok * OUTLD + co] = f2b(v);
                else if (MODE == 1) outb[(size_t)tok * OUTLD + co] = f2b(gelu_exact(v));
                else outf[(size_t)tok * OUTLD + co] += v;
            }
        }
    }
}

// ---------- Stable counting sort by tk_id ----------
__global__ void k_sort_count(const int* tk_id, int* chunk_cnt) {
    int c = blockIdx.x, b = blockIdx.y;
    int tid = threadIdx.x;               // 128
    __shared__ int cnt[M];
    cnt[tid] = 0;
    __syncthreads();
    atomicAdd(&cnt[tk_id[b * N + c * 128 + tid]], 1);
    __syncthreads();
    chunk_cnt[(b * 128 + c) * M + tid] = cnt[tid];
}

__global__ void k_sort_scan(int* chunk_cnt) {
    int b = blockIdx.x;
    int k = threadIdx.x;
    int tot = 0;
    for (int c = 0; c < 128; ++c) tot += chunk_cnt[(b * 128 + c) * M + k];
    __shared__ int totals[M];
    __shared__ int base[M];
    totals[k] = tot;
    __syncthreads();
    if (k == 0) {
        int run = 0;
        for (int kk = 0; kk < M; ++kk) { base[kk] = run; run += totals[kk]; }
    }
    __syncthreads();
    int run = base[k];
    for (int c = 0; c < 128; ++c) {
        int v = chunk_cnt[(b * 128 + c) * M + k];
        chunk_cnt[(b * 128 + c) * M + k] = run;
        run += v;
    }
}

__global__ void k_sort_scatter(const int* tk_id, const int* chunk_cnt, int* sort_idx) {
    int c = blockIdx.x, b = blockIdx.y;
    int k = threadIdx.x;
    __shared__ int keys[128];
    keys[k] = tk_id[b * N + c * 128 + k];
    __syncthreads();
    int off = chunk_cnt[(b * 128 + c) * M + k];
    for (int j = 0; j < 128; ++j) {
        if (keys[j] == k) sort_idx[b * N + off++] = c * 128 + j;
    }
}

// ---------- MFMA grouped self-attention: block = (group, head, batch) ----------
__global__ void __launch_bounds__(256) k_attn_mfma(const bf16* qkv, const int* sort_idx, bf16* o_buf) {
    int g = blockIdx.x, h = blockIdx.y, b = blockIdx.z;
    __shared__ int sidx[GS];
    __shared__ __align__(16) unsigned short Kl[256 * 64];   // [key][64d], 16B-blk ^ (key&7)
    __shared__ __align__(16) unsigned short Vt[48 * 256];   // [d][256key], 16B-blk ^ (d&7)
    __shared__ __align__(16) unsigned short Pl[4][64 * 32]; // per-wave [64q][32key], 16B-blk ^ (q&3)
    int tid = threadIdx.x;
    sidx[tid] = sort_idx[b * N + g * GS + tid];
    __syncthreads();
    {
        int row = tid;
        int srow = sidx[row];
        size_t kb = ((size_t)(b * N + srow)) * TC3 + C + h * HD;
        size_t vb = ((size_t)(b * N + srow)) * TC3 + 2 * C + h * HD;
        #pragma unroll
        for (int db = 0; db < 6; ++db) {
            uint4 kv = *(const uint4*)(qkv + kb + db * 8);
            *(uint4*)&Kl[row * 64 + ((db ^ (row & 7)) * 8)] = kv;
            uint4 vv4 = *(const uint4*)(qkv + vb + db * 8);
            unsigned short* vu = (unsigned short*)&vv4;
            #pragma unroll
            for (int j = 0; j < 8; ++j) {
                int d = db * 8 + j;
                Vt[d * 256 + (((row >> 3) ^ (d & 7)) * 8) + (row & 7)] = vu[j];
            }
        }
        uint4 z = {0u,0u,0u,0u};
        *(uint4*)&Kl[row * 64 + ((6 ^ (row & 7)) * 8)] = z;
        *(uint4*)&Kl[row * 64 + ((7 ^ (row & 7)) * 8)] = z;
    }
    __syncthreads();
    int w = tid >> 6, l = tid & 63;
    int lq = l & 15, g8 = l >> 4;
    bf16x8 qf[4][2];
    #pragma unroll
    for (int qt = 0; qt < 4; ++qt) {
        int qrow = sidx[w * 64 + qt * 16 + lq];
        size_t qb = ((size_t)(b * N + qrow)) * TC3 + h * HD;
        qf[qt][0] = *(const bf16x8*)(qkv + qb + g8 * 8);
        int d1 = 32 + g8 * 8;
        if (d1 < HD) qf[qt][1] = *(const bf16x8*)(qkv + qb + d1);
        else { uint4 z = {0u,0u,0u,0u}; qf[qt][1] = *(bf16x8*)&z; }
    }
    float mrun[4], lrun[4];
    f32x4 Oa[4][3];
    #pragma unroll
    for (int qt = 0; qt < 4; ++qt) {
        mrun[qt] = -1e30f; lrun[qt] = 0.f;
        #pragma unroll
        for (int dt = 0; dt < 3; ++dt) Oa[qt][dt] = (f32x4){0.f,0.f,0.f,0.f};
    }
    unsigned short* Pw = &Pl[w][0];
    for (int ck = 0; ck < 8; ++ck) {
        int kbase = ck * 32;
        bf16x8 kf[2][2];
        #pragma unroll
        for (int kt = 0; kt < 2; ++kt) {
            int key = kbase + kt * 16 + lq;
            #pragma unroll
            for (int ks = 0; ks < 2; ++ks)
                kf[kt][ks] = *(bf16x8*)&Kl[key * 64 + (((ks * 4 + g8) ^ (key & 7)) * 8)];
        }
        bf16x8 vf[3];
        #pragma unroll
        for (int dt = 0; dt < 3; ++dt) {
            int d = dt * 16 + lq;
            vf[dt] = *(bf16x8*)&Vt[d * 256 + ((((kbase >> 3) + g8) ^ (d & 7)) * 8)];
        }
        #pragma unroll
        for (int qt = 0; qt < 4; ++qt) {
            f32x4 s0 = {0.f,0.f,0.f,0.f}, s1 = s0;
            s0 = __builtin_amdgcn_mfma_f32_16x16x32_bf16(kf[0][0], qf[qt][0], s0, 0, 0, 0);
            s0 = __builtin_amdgcn_mfma_f32_16x16x32_bf16(kf[0][1], qf[qt][1], s0, 0, 0, 0);
            s1 = __builtin_amdgcn_mfma_f32_16x16x32_bf16(kf[1][0], qf[qt][0], s1, 0, 0, 0);
            s1 = __builtin_amdgcn_mfma_f32_16x16x32_bf16(kf[1][1], qf[qt][1], s1, 0, 0, 0);
            float sv0[4], sv1[4];
            float cmax = -1e30f;
            #pragma unroll
            for (int r = 0; r < 4; ++r) {
                sv0[r] = s0[r] * ATT_SCALE; sv1[r] = s1[r] * ATT_SCALE;
                cmax = fmaxf(cmax, fmaxf(sv0[r], sv1[r]));
            }
            cmax = fmaxf(cmax, __shfl_xor(cmax, 16));
            cmax = fmaxf(cmax, __shfl_xor(cmax, 32));
            float mnew = fmaxf(mrun[qt], cmax);
            float sf = expf(mrun[qt] - mnew);
            float p0[4], p1[4], csum = 0.f;
            #pragma unroll
            for (int r = 0; r < 4; ++r) {
                p0[r] = expf(sv0[r] - mnew); p1[r] = expf(sv1[r] - mnew);
                csum += p0[r] + p1[r];
            }
            csum += __shfl_xor(csum, 16);
            csum += __shfl_xor(csum, 32);
            lrun[qt] = lrun[qt] * sf + csum;
            mrun[qt] = mnew;
            int q = qt * 16 + lq;
            {
                unsigned short pw[4];
                #pragma unroll
                for (int r = 0; r < 4; ++r) pw[r] = f2bits(p0[r]);
                int slot = g8;
                int addr = q * 32 + (((slot >> 1) ^ (q & 3)) * 8) + (slot & 1) * 4;
                *(uint2*)&Pw[addr] = *(uint2*)pw;
                #pragma unroll
                for (int r = 0; r < 4; ++r) pw[r] = f2bits(p1[r]);
                slot = 4 + g8;
                addr = q * 32 + (((slot >> 1) ^ (q & 3)) * 8) + (slot & 1) * 4;
                *(uint2*)&Pw[addr] = *(uint2*)pw;
            }
            float sfr[4];
            #pragma unroll
            for (int r = 0; r < 4; ++r) sfr[r] = __shfl(sf, 4 * g8 + r);
            #pragma unroll
            for (int dt = 0; dt < 3; ++dt)
                #pragma unroll
                for (int r = 0; r < 4; ++r) Oa[qt][dt][r] *= sfr[r];
            bf16x8 pa = *(bf16x8*)&Pw[q * 32 + ((g8 ^ (lq & 3)) * 8)];
            #pragma unroll
            for (int dt = 0; dt < 3; ++dt)
                Oa[qt][dt] = __builtin_amdgcn_mfma_f32_16x16x32_bf16(pa, vf[dt], Oa[qt][dt], 0, 0, 0);
        }
    }
    #pragma unroll
    for (int qt = 0; qt < 4; ++qt) {
        float invq = 1.0f / lrun[qt];
        float invr[4];
        #pragma unroll
        for (int r = 0; r < 4; ++r) invr[r] = __shfl(invq, 4 * g8 + r);
        #pragma unroll
        for (int r = 0; r < 4; ++r) {
            int grow = sidx[w * 64 + qt * 16 + 4 * g8 + r];
            size_t obase = ((size_t)(b * N + grow)) * C + h * HD;
            #pragma unroll
            for (int dt = 0; dt < 3; ++dt)
                o_buf[obase + dt * 16 + lq] = f2b(Oa[qt][dt][r] * invr[r]);
        }
    }
}

// ---------- td feature gather into hcat tail columns ----------
__global__ void k_tdfill(const int* tk_id, const float* tdf, bf16* hcat) {
    int idx = blockIdx.x * 256 + threadIdx.x;
    if (idx >= B * N * TDF) return;
    int tok = idx >> 4, f = idx & 15;
    hcat[(size_t)tok * HIDT + HID + f] = f2b(tdf[tk_id[tok] * TDF + f]);
}

// ---------- depthwise 5x5 conv v2: 16y x 32x x 16ch tile, XOR-swizzled LDS,
// ---------- 4 x-outputs/thread with column register reuse ----------
__global__ void __launch_bounds__(256) k_conv(const bf16* hcat, const float* dw_w, const float* dw_b,
                                              bf16* convsum) {
    int st = blockIdx.x;                 // 32 spatial tiles: sx = st&3 (32 wide), sy = st>>2 (16 tall)
    int c16 = blockIdx.y;                // 49 channel chunks
    int b = blockIdx.z;
    int tx0 = (st & 3) * 32, ty0 = (st >> 2) * 16;
    int tid = threadIdx.x;
    // Hs: 20 rows x 36 px x 16ch bf16; per row 72 16B-blocks, blk ^= ((blk>>3)+py)&7
    __shared__ __align__(16) unsigned short Hs[20 * 576];
    __shared__ __align__(16) float Wf[25 * 16];   // [tap][ch]
    __shared__ float Wb[16];
    for (int e = tid; e < 400; e += 256) {
        int tap = e >> 4, ch = e & 15;
        Wf[e] = dw_w[(size_t)(c16 * 16 + ch) * 25 + tap];
    }
    if (tid < 16) Wb[tid] = dw_b[c16 * 16 + tid];
    for (int e = tid; e < 1440; e += 256) {
        int pos = e >> 1, sc = e & 1;
        int py = pos / 36, px = pos - py * 36;
        int gy = ty0 + py - 2, gx = tx0 + px - 2;
        uint4 v = {0u, 0u, 0u, 0u};
        if (gy >= 0 && gy < Hh && gx >= 0 && gx < Ww)
            v = *(const uint4*)(hcat + ((size_t)b * N + gy * Ww + gx) * HIDT + c16 * 16 + sc * 8);
        int blk = px * 2 + sc;
        blk ^= ((blk >> 3) + py) & 7;
        *(uint4*)&Hs[py * 576 + blk * 8] = v;
    }
    __syncthreads();
    int cc = tid & 1, xq = (tid >> 1) & 7, ly = tid >> 4;   // 2 x 8 x 16
    float acc[4][8];
    #pragma unroll
    for (int ox = 0; ox < 4; ++ox)
        #pragma unroll
        for (int j = 0; j < 8; ++j) acc[ox][j] = 0.f;
    #pragma unroll
    for (int ky = 0; ky < 5; ++ky) {
        int py = ly + ky;
        float4 w[5][2];
        #pragma unroll
        for (int kx = 0; kx < 5; ++kx) {
            w[kx][0] = *(float4*)&Wf[(ky * 5 + kx) * 16 + cc * 8];
            w[kx][1] = *(float4*)&Wf[(ky * 5 + kx) * 16 + cc * 8 + 4];
        }
        #pragma unroll
        for (int c = 0; c < 8; ++c) {
            int px = xq * 4 + c;
            int blk = px * 2 + cc;
            blk ^= ((blk >> 3) + py) & 7;
            bf16x8 cv = *(bf16x8*)&Hs[py * 576 + blk * 8];
            unsigned short* cu = (unsigned short*)&cv;
            float f[8];
            #pragma unroll
            for (int j = 0; j < 8; ++j) f[j] = bits2f(cu[j]);
            #pragma unroll
            for (int kx = 0; kx < 5; ++kx) {
                int ox = c - kx;
                if (ox >= 0 && ox < 4) {
                    const float* wp = (const float*)&w[kx][0];
                    #pragma unroll
                    for (int j = 0; j < 8; ++j) acc[ox][j] += f[j] * wp[j];
                }
            }
        }
    }
    // epilogue: bias + gelu + residual(center) + store
    int gy = ty0 + ly;
    #pragma unroll
    for (int ox = 0; ox < 4; ++ox) {
        int px = xq * 4 + ox + 2, py = ly + 2;
        int blk = px * 2 + cc;
        blk ^= ((blk >> 3) + py) & 7;
        bf16x8 cv = *(bf16x8*)&Hs[py * 576 + blk * 8];
        unsigned short* cu = (unsigned short*)&cv;
        unsigned short ow[8];
        #pragma unroll
        for (int j = 0; j < 8; ++j)
            ow[j] = f2bits(bits2f(cu[j]) + gelu_exact(acc[ox][j] + Wb[cc * 8 + j]));
        int gx = tx0 + xq * 4 + ox;
        *(uint4*)(convsum + ((size_t)b * N + gy * Ww + gx) * HIDT + c16 * 16 + cc * 8) = *(uint4*)ow;
    }
}

// ---------- fc2 (K=784) MFMA + bias + LN3 + residual + transposed store ----------
__global__ void __launch_bounds__(256) k_fc2ln(const bf16* convsum, const bf16* Wt,  // Wt [192][784]
                                               const float* bias, const float* g3, const float* b3,
                                               const float* accres, float* out) {
    __shared__ __align__(16) unsigned short As[64 * 64];
    __shared__ __align__(16) unsigned short Bs[192 * 64];
    int tid = threadIdx.x;
    int m0 = blockIdx.x * 64;
    int w = tid >> 6, lane = tid & 63;
    int lr = lane & 15, g8 = lane >> 4;
    f32x4 acc[12];
    #pragma unroll
    for (int nt = 0; nt < 12; ++nt) acc[nt] = (f32x4){0.f, 0.f, 0.f, 0.f};
    for (int kc = 0; kc < 13; ++kc) {
        int kb = kc * 64;
        for (int e = tid; e < 512; e += 256) {
            int m = e >> 3, k8 = (e & 7) * 8;
            uint4 v = {0u,0u,0u,0u};
            if (kb + k8 < HIDT) v = *(const uint4*)(convsum + (size_t)(m0 + m) * HIDT + kb + k8);
            *(uint4*)&As[m * 64 + (((e & 7) ^ (m & 7)) * 8)] = v;
        }
        for (int e = tid; e < 1536; e += 256) {
            int n = e >> 3, k8 = (e & 7) * 8;
            uint4 v = {0u,0u,0u,0u};
            if (kb + k8 < HIDT) v = *(const uint4*)(Wt + (size_t)n * HIDT + kb + k8);
            *(uint4*)&Bs[n * 64 + (((e & 7) ^ (n & 7)) * 8)] = v;
        }
        __syncthreads();
        #pragma unroll
        for (int ks = 0; ks < 2; ++ks) {
            int kg = ks * 4 + g8;
            int arow = w * 16 + lr;
            bf16x8 a = *(bf16x8*)&As[arow * 64 + ((kg ^ (arow & 7)) * 8)];
            #pragma unroll
            for (int nt = 0; nt < 12; ++nt) {
                int nrow = nt * 16 + lr;
                bf16x8 bfr = *(bf16x8*)&Bs[nrow * 64 + ((kg ^ (nrow & 7)) * 8)];
                acc[nt] = __builtin_amdgcn_mfma_f32_16x16x32_bf16(a, bfr, acc[nt], 0, 0, 0);
            }
        }
        __syncthreads();
    }
    #pragma unroll
    for (int nt = 0; nt < 12; ++nt) {
        float bv = bias[nt * 16 + lr];
        #pragma unroll
        for (int r = 0; r < 4; ++r) acc[nt][r] += bv;
    }
    #pragma unroll
    for (int r = 0; r < 4; ++r) {
        float s = 0.f, ss = 0.f;
        #pragma unroll
        for (int nt = 0; nt < 12; ++nt) { float v = acc[nt][r]; s += v; ss += v * v; }
        s += __shfl_xor(s, 1); ss += __shfl_xor(ss, 1);
        s += __shfl_xor(s, 2); ss += __shfl_xor(ss, 2);
        s += __shfl_xor(s, 4); ss += __shfl_xor(ss, 4);
        s += __shfl_xor(s, 8); ss += __shfl_xor(ss, 8);
        float mu = s / C;
        float rstd = rsqrtf(ss / C - mu * mu + 1e-5f);
        int tok = m0 + w * 16 + g8 * 4 + r;
        int b = tok / N, i = tok % N;
        #pragma unroll
        for (int nt = 0; nt < 12; ++nt) {
            int c = nt * 16 + lr;
            float o = accres[(size_t)tok * C + c] + (acc[nt][r] - mu) * rstd * g3[c] + b3[c];
            out[((size_t)b * C + c) * N + i] = o;
        }
    }
}

__global__ void k_sentinel(float* out, int nelem) {
    int i = blockIdx.x * blockDim.x + threadIdx.x;
    if (i < nelem) out[i] = 1234.0f;
}

extern "C" void kernel_launch(void* const* d_in, const int* in_sizes, int n_in,
                              void* d_out, int out_size, void* d_ws, size_t ws_size,
                              hipStream_t stream) {
    const float* x        = (const float*)d_in[0];
    const float* td       = (const float*)d_in[2];
    const float* g1       = (const float*)d_in[3];
    const float* b1       = (const float*)d_in[4];
    const float* g2       = (const float*)d_in[5];
    const float* b2v      = (const float*)d_in[6];
    const float* g3       = (const float*)d_in[7];
    const float* b3       = (const float*)d_in[8];
    const float* wq_w     = (const float*)d_in[9];
    const float* wq_b     = (const float*)d_in[10];
    const float* wk_w     = (const float*)d_in[11];
    const float* wk_b     = (const float*)d_in[12];
    const float* wv_w     = (const float*)d_in[13];
    const float* wv_b     = (const float*)d_in[14];
    const float* ca_scale = (const float*)d_in[15];
    const float* wqkv_w   = (const float*)d_in[16];
    const float* wqkv_b   = (const float*)d_in[17];
    const float* proj_w   = (const float*)d_in[18];
    const float* proj_b   = (const float*)d_in[19];
    const float* fc_td_w  = (const float*)d_in[20];
    const float* fc_td_b  = (const float*)d_in[21];
    const float* fc1_w    = (const float*)d_in[22];
    const float* fc1_b    = (const float*)d_in[23];
    const float* dw_w     = (const float*)d_in[24];
    const float* dw_b     = (const float*)d_in[25];
    const float* fc2_w    = (const float*)d_in[26];
    const float* fc2_b    = (const float*)d_in[27];
    float* out = (float*)d_out;

    char* ws = (char*)d_ws;
    size_t off = 0;
    auto alloc = [&](size_t bytes) { size_t o = off; off += (bytes + 255) & ~(size_t)255; return o; };
    size_t o_t     = alloc((size_t)B * N * C * 2);
    size_t o_xn32  = alloc((size_t)B * N * C * 4);
    size_t o_acc   = alloc((size_t)B * N * C * 4);
    size_t o_qkv   = alloc((size_t)B * N * TC3 * 2);
    size_t o_obuf  = alloc((size_t)B * N * C * 2);
    size_t o_hcat  = alloc((size_t)B * N * HIDT * 2);
    size_t o_conv  = alloc((size_t)B * N * HIDT * 2);
    size_t o_kn    = alloc((size_t)M * RD * 4);
    size_t o_vv    = alloc((size_t)M * C * 4);
    size_t o_tdf   = alloc((size_t)M * TDF * 4);
    size_t o_tk    = alloc((size_t)B * N * 4);
    size_t o_sidx  = alloc((size_t)B * N * 4);
    size_t o_ccnt  = alloc((size_t)B * 128 * M * 4);
    size_t o_wqkvT = alloc((size_t)TC3 * C * 2);
    size_t o_projT = alloc((size_t)C * C * 2);
    size_t o_fc1T  = alloc((size_t)HID * C * 2);
    size_t o_fc2T  = alloc((size_t)C * HIDT * 2);

    if (ws_size < off) {
        k_sentinel<<<(out_size + 255) / 256, 256, 0, stream>>>(out, out_size);
        return;
    }

    bf16*  t_buf   = (bf16*)(ws + o_t);
    float* xn32    = (float*)(ws + o_xn32);
    float* acc     = (float*)(ws + o_acc);
    bf16*  qkv     = (bf16*)(ws + o_qkv);
    bf16*  o_bufp  = (bf16*)(ws + o_obuf);
    bf16*  hcat    = (bf16*)(ws + o_hcat);
    bf16*  convsum = (bf16*)(ws + o_conv);
    float* kn      = (float*)(ws + o_kn);
    float* vv      = (float*)(ws + o_vv);
    float* tdf     = (float*)(ws + o_tdf);
    int*   tk_id   = (int*)(ws + o_tk);
    int*   sidx    = (int*)(ws + o_sidx);
    int*   ccnt    = (int*)(ws + o_ccnt);
    bf16*  wqkvT   = (bf16*)(ws + o_wqkvT);
    bf16*  projT   = (bf16*)(ws + o_projT);
    bf16*  fc1T    = (bf16*)(ws + o_fc1T);
    bf16*  fc2T    = (bf16*)(ws + o_fc2T);

    k_wtrans<<<dim3(TC3 / 64, C / 64), 256, 0, stream>>>(wqkv_w, wqkvT, C, TC3);
    k_wtrans<<<dim3(C / 64, C / 64), 256, 0, stream>>>(proj_w, projT, C, C);
    k_wtrans<<<dim3(HID / 64, C / 64), 256, 0, stream>>>(fc1_w, fc1T, C, HID);
    k_wtrans<<<dim3(C / 64, (HIDT + 63) / 64), 256, 0, stream>>>(fc2_w, fc2T, HIDT, C);

    k_precompute<<<M, 64, 0, stream>>>(td, wk_w, wk_b, wv_w, wv_b, fc_td_w, fc_td_b, kn, vv, tdf);
    k_ln<<<B * N / 64, 256, 0, stream>>>(x, t_buf, xn32, acc);
    k_atdca<<<B * N / 4, 256, 0, stream>>>(xn32, g1, b1, wq_w, wq_b, ca_scale, kn, vv, acc, tk_id);
    k_gemm192<TC3, TC3, 0, true><<<dim3(B * N / 64, TC3 / 64), 256, 0, stream>>>(
        t_buf, g1, b1, wqkvT, wqkv_b, qkv, nullptr);
    k_sort_count<<<dim3(128, B), 128, 0, stream>>>(tk_id, ccnt);
    k_sort_scan<<<B, 128, 0, stream>>>(ccnt);
    k_sort_scatter<<<dim3(128, B), 128, 0, stream>>>(tk_id, ccnt, sidx);
    k_attn_mfma<<<dim3(NG, HEADS, B), 256, 0, stream>>>(qkv, sidx, o_bufp);
    k_gemm192<C, C, 2, false><<<dim3(B * N / 64, C / 64), 256, 0, stream>>>(
        o_bufp, nullptr, nullptr, projT, proj_b, nullptr, acc);
    k_gemm192<HID, HIDT, 1, true><<<dim3(B * N / 64, HID / 64), 256, 0, stream>>>(
        t_buf, g2, b2v, fc1T, fc1_b, hcat, nullptr);
    k_tdfill<<<(B * N * TDF + 255) / 256, 256, 0, stream>>>(tk_id, tdf, hcat);
    k_conv<<<dim3(32, 49, B), 256, 0, stream>>>(hcat, dw_w, dw_b, convsum);
    k_fc2ln<<<B * N / 64, 256, 0, stream>>>(convsum, fc2T, fc2_b, g3, b3, acc, out);
}